// Round 4
// baseline (7212.035 us; speedup 1.0000x reference)
//
#include <hip/hip_runtime.h>
#include <hip/hip_bf16.h>
#include <cstddef>

namespace {

constexpr int B = 16, T = 32, S = 400, E = 128, H = 512, V = 32000, OOV = 50, VEXT = V + OOV;

__device__ __forceinline__ float fsig(float x){ return 1.0f/(1.0f+__expf(-x)); }
__device__ __forceinline__ float ftanh(float x){
  float ax = fabsf(x);
  float t = __expf(-2.0f*ax);
  float r = (1.0f - t)/(1.0f + t);
  return copysignf(r, x);
}

// grid-stride init: copy h0/c0, zero cov, pgen_raw, vsum, hh_all.
__global__ __launch_bounds__(256) void k_init(const float* __restrict__ h0, const float* __restrict__ c0,
    float* __restrict__ h, float* __restrict__ c, float* __restrict__ cov,
    float* __restrict__ praw, float* __restrict__ vsum, float* __restrict__ hh_all){
  const int stride = gridDim.x*256;
  for (int i = blockIdx.x*256 + threadIdx.x; i < T*B*H; i += stride){
    hh_all[i] = 0.0f;
    if (i < B*H){ h[i]=h0[i]; c[i]=c0[i]; }
    if (i < B*S) cov[i]=0.0f;
    if (i < T*B){ praw[i]=0.0f; vsum[i]=0.0f; }
  }
}

// x0[b][j] = emb[b][0][:] . W_xctx[j][:E] + b_xctx[j]   (ctx_0 = 0)
__global__ __launch_bounds__(128) void k_x0(const float* __restrict__ emb,
    const float* __restrict__ W_xctx, const float* __restrict__ b_xctx,
    float* __restrict__ x0){
  const int b = blockIdx.x, tid = threadIdx.x;
  __shared__ float se[E];
  se[tid] = emb[(size_t)(b*T)*E + tid];
  __syncthreads();
  const float* w = W_xctx + (size_t)tid*(E+H);
  float acc = b_xctx[tid];
  #pragma unroll 8
  for (int k=0;k<E;k+=4){
    float4 wv = *reinterpret_cast<const float4*>(w+k);
    acc += se[k]*wv.x + se[k+1]*wv.y + se[k+2]*wv.z + se[k+3]*wv.w;
  }
  x0[b*E + tid] = acc;
}

// Wt[j][k] = W_energy[k][H+j]  (512x512), tiled transpose. grid (16,16) x 256.
__global__ __launch_bounds__(256) void k_trw(const float* __restrict__ W_energy,
                                             float* __restrict__ Wt){
  __shared__ float tile[32][33];
  const int j0 = blockIdx.x*32, k0 = blockIdx.y*32;
  const int tx = threadIdx.x & 31, ty = threadIdx.x >> 5;
  #pragma unroll
  for (int r=0;r<4;++r)
    tile[ty+8*r][tx] = W_energy[(size_t)(k0+ty+8*r)*(2*H) + H + j0 + tx];
  __syncthreads();
  #pragma unroll
  for (int r=0;r<4;++r)
    Wt[(size_t)(j0+ty+8*r)*H + k0 + tx] = tile[tx][ty+8*r];
}

// enc_proj: 400 blocks x 512 threads; 16 s-rows register-blocked x 512 k.
__global__ __launch_bounds__(512) void k_encproj(const float* __restrict__ enc,
                          const float* __restrict__ Wt,
                          const float* __restrict__ b_energy,
                          float* __restrict__ enc_proj){
  __shared__ float ldsE[16][H];
  const int r0 = blockIdx.x * 16;
  const int tid = threadIdx.x;
  for (int i = tid; i < 16*(H/4); i += 512){
    const int r = i >> 7, cc = i & 127;
    *reinterpret_cast<float4*>(&ldsE[r][cc*4]) =
        *reinterpret_cast<const float4*>(&enc[(size_t)(r0+r)*H + cc*4]);
  }
  __syncthreads();
  const int k = tid;
  float acc[16];
  #pragma unroll
  for (int r=0;r<16;++r) acc[r]=0.0f;
  #pragma unroll 2
  for (int j=0;j<H;j+=4){
    const float w0 = Wt[(size_t) j   *H + k];
    const float w1 = Wt[(size_t)(j+1)*H + k];
    const float w2 = Wt[(size_t)(j+2)*H + k];
    const float w3 = Wt[(size_t)(j+3)*H + k];
    #pragma unroll
    for (int r=0;r<16;++r){
      const float4 e = *reinterpret_cast<const float4*>(&ldsE[r][j]);
      acc[r] += e.x*w0 + e.y*w1 + e.z*w2 + e.w*w3;
    }
  }
  const float be = b_energy[k];
  #pragma unroll
  for (int r=0;r<16;++r) enc_proj[(size_t)(r0+r)*H + k] = acc[r] + be;
}

// grid 64 x 256: gates GEMM multi-b (16 j x 4 gates x 8 b) + fused LSTM.
__global__ __launch_bounds__(256) void k_gates(
    const float* __restrict__ x, const float* __restrict__ hold,
    const float* __restrict__ cold,
    const float* __restrict__ W_ih, const float* __restrict__ W_hh,
    const float* __restrict__ b_ih, const float* __restrict__ b_hh,
    float* __restrict__ hnew, float* __restrict__ cnew){
  const int blk = blockIdx.x, tid = threadIdx.x;
  const int gb = blk >> 1, bh = blk & 1, b0 = bh*8;
  __shared__ float xh[8][640];
  __shared__ float sg[4][64][9];
  for (int b=0;b<8;++b)
    for (int k=tid;k<640;k+=256)
      xh[b][k] = (k<E) ? x[(b0+b)*E + k] : hold[(b0+b)*H + (k-E)];
  __syncthreads();
  const int w = tid >> 6, l = tid & 63, g = l >> 4, jj = l & 15;
  const int row = g*H + gb*16 + jj;
  float acc[8];
  #pragma unroll
  for (int b=0;b<8;++b) acc[b]=0.0f;
  const int ks = w*160, ke = ks + 160;
  if (ks < 128){
    const float* wr = W_ih + (size_t)row*E;
    for (int k=0;k<128;k+=4){
      const float4 wv = *reinterpret_cast<const float4*>(wr + k);
      #pragma unroll
      for (int b=0;b<8;++b){
        const float4 xv = *reinterpret_cast<const float4*>(&xh[b][k]);
        acc[b] += xv.x*wv.x + xv.y*wv.y + xv.z*wv.z + xv.w*wv.w;
      }
    }
  }
  {
    const int hs = (ks < 128) ? 128 : ks;
    const float* wr = W_hh + (size_t)row*H - 128;
    for (int k=hs;k<ke;k+=4){
      const float4 wv = *reinterpret_cast<const float4*>(wr + k);
      #pragma unroll
      for (int b=0;b<8;++b){
        const float4 xv = *reinterpret_cast<const float4*>(&xh[b][k]);
        acc[b] += xv.x*wv.x + xv.y*wv.y + xv.z*wv.z + xv.w*wv.w;
      }
    }
  }
  #pragma unroll
  for (int b=0;b<8;++b) sg[w][l][b] = acc[b];
  __syncthreads();
  if (tid < 128){
    const int b = tid >> 4, j2 = tid & 15;
    float gs[4];
    #pragma unroll
    for (int g2=0;g2<4;++g2){
      const int ll = g2*16 + j2;
      const int rw = g2*H + gb*16 + j2;
      gs[g2] = sg[0][ll][b]+sg[1][ll][b]+sg[2][ll][b]+sg[3][ll][b] + b_ih[rw] + b_hh[rw];
    }
    const float ig = fsig(gs[0]);
    const float fg = fsig(gs[1]);
    const float gg = ftanh(gs[2]);
    const float og = fsig(gs[3]);
    const int idx = (b0+b)*H + gb*16 + j2;
    const float cn = fg*cold[idx] + ig*gg;
    cnew[idx] = cn;
    hnew[idx] = og*ftanh(cn);
  }
}

// grid 16 x 1024: dec GEMV (LDS-only) then all 400 attention scores.
// Also zeroes xnext accumulator for this step.
__global__ __launch_bounds__(1024) void k_decscore(const float* __restrict__ h,
    const float* __restrict__ W_energy, const float* __restrict__ encp,
    const float* __restrict__ W_cov, const float* __restrict__ v_attn,
    const float* __restrict__ cov, float* __restrict__ score,
    float* __restrict__ xnext){
  const int b = blockIdx.x, tid = threadIdx.x;
  __shared__ float sh[H], sdec[H], swc[H], sva[H];
  if (tid < H) sh[tid] = h[b*H + tid];
  else { const int k = tid - H; swc[k] = W_cov[k]; sva[k] = v_attn[k]; }
  if (tid < E) xnext[b*E + tid] = 0.0f;
  __syncthreads();
  {
    const int j = tid >> 1, half = tid & 1;
    const float* wd = W_energy + (size_t)j*(2*H) + half*256;
    const float* hb = sh + half*256;
    float acc = 0.0f;
    #pragma unroll 8
    for (int k=0;k<256;k+=4){
      const float4 w = *reinterpret_cast<const float4*>(wd+k);
      acc += hb[k]*w.x + hb[k+1]*w.y + hb[k+2]*w.z + hb[k+3]*w.w;
    }
    acc += __shfl_xor(acc, 1);
    if (half==0) sdec[j] = acc;
  }
  __syncthreads();
  const int wid = tid >> 6, lane = tid & 63, k0 = lane*8;
  for (int s = wid; s < S; s += 16){
    const float cv = cov[b*S + s];
    const float* ep = encp + (size_t)(b*S+s)*H + k0;
    float a = 0.0f;
    #pragma unroll
    for (int u=0;u<8;++u)
      a += ftanh(sdec[k0+u] + ep[u] + cv*swc[k0+u]) * sva[k0+u];
    #pragma unroll
    for (int off=32; off>0; off>>=1) a += __shfl_down(a, off);
    if (lane==0) score[b*S + s] = a;
  }
}

// grid (16 b, 8 hc) x 256: redundant softmax; ctx slice; split-K atomic
// assembly of hh(t), xnext(t+1), pgen_raw(t). hc0 adds h/emb/bias parts,
// writes probs_all[t], updates cov.
__global__ __launch_bounds__(256) void k_ctxpost(const float* __restrict__ score,
    const float* __restrict__ masks, const float* __restrict__ enc,
    const float* __restrict__ h, const float* __restrict__ xcur,
    const float* __restrict__ emb, int tnext,
    const float* __restrict__ W_ad, const float* __restrict__ b_ad,
    const float* __restrict__ W_pgen, const float* __restrict__ b_pgen,
    const float* __restrict__ W_xctx, const float* __restrict__ b_xctx,
    float* __restrict__ cov, float* __restrict__ probs_t,
    float* __restrict__ hh_t, float* __restrict__ praw_t,
    float* __restrict__ xnext){
  const int b = blockIdx.x, hc = blockIdx.y, tid = threadIdx.x;
  __shared__ float red[256], sp[512], sctx[64], shh[H], se[E];
  if (hc==0){
    for (int i=tid;i<H;i+=256) shh[i] = h[b*H + i];
    if (tid < E) se[tid] = emb[(size_t)(b*T + tnext)*E + tid];
  }
  const float sc0 = (tid < S)      ? score[b*S + tid]       : -1e30f;
  const float sc1 = (tid+256 < S)  ? score[b*S + tid + 256] : -1e30f;
  red[tid] = fmaxf(sc0, sc1);
  __syncthreads();
  for (int off=128; off>0; off>>=1){ if (tid<off) red[tid]=fmaxf(red[tid],red[tid+off]); __syncthreads(); }
  const float mx = red[0];
  __syncthreads();
  const float e0 = (tid < S)     ? __expf(sc0 - mx) : 0.0f;
  const float e1 = (tid+256 < S) ? __expf(sc1 - mx) : 0.0f;
  red[tid] = e0 + e1;
  __syncthreads();
  for (int off=128; off>0; off>>=1){ if (tid<off) red[tid]+=red[tid+off]; __syncthreads(); }
  const float den = red[0];
  __syncthreads();
  const float p0 = (tid < S)     ? (e0/den)*masks[b*S+tid]     : 0.0f;
  const float p1 = (tid+256 < S) ? (e1/den)*masks[b*S+tid+256] : 0.0f;
  red[tid] = p0 + p1;
  __syncthreads();
  for (int off=128; off>0; off>>=1){ if (tid<off) red[tid]+=red[tid+off]; __syncthreads(); }
  const float inv = 1.0f/(red[0] + 1e-12f);
  __syncthreads();
  const float pr0 = p0*inv, pr1 = p1*inv;
  sp[tid] = pr0; sp[tid+256] = pr1;
  if (hc==0){
    if (tid < S){ probs_t[b*S+tid] = pr0; cov[b*S+tid] += pr0; }
    if (tid+256 < S){ probs_t[b*S+tid+256] = pr1; cov[b*S+tid+256] += pr1; }
  }
  __syncthreads();
  // ctx slice: cols [hc*64, hc*64+64)
  {
    const int c = tid & 63, sg_ = tid >> 6;
    const float* eb = enc + (size_t)b*S*H + hc*64 + c;
    float a = 0.0f;
    for (int s=sg_; s<S; s+=4) a += sp[s]*eb[(size_t)s*H];
    red[tid] = a;
    __syncthreads();
    if (tid < 64) sctx[tid] = red[tid]+red[tid+64]+red[tid+128]+red[tid+192];
  }
  __syncthreads();
  // hh: ctx-part (all hc) + h-part & bias (hc0)
  for (int j=tid; j<H; j+=256){
    const float* wa = W_ad + (size_t)j*(2*H) + H + hc*64;
    float acc = 0.0f;
    #pragma unroll
    for (int k=0;k<64;k+=4){
      const float4 w = *reinterpret_cast<const float4*>(wa+k);
      acc += sctx[k]*w.x + sctx[k+1]*w.y + sctx[k+2]*w.z + sctx[k+3]*w.w;
    }
    if (hc==0){
      const float* wh = W_ad + (size_t)j*(2*H);
      #pragma unroll 8
      for (int k=0;k<H;k+=4){
        const float4 w = *reinterpret_cast<const float4*>(wh+k);
        acc += shh[k]*w.x + shh[k+1]*w.y + shh[k+2]*w.z + shh[k+3]*w.w;
      }
      acc += b_ad[j];
    }
    atomicAdd(&hh_t[b*H + j], acc);
  }
  // xnext: ctx-part (all hc) + emb-part & bias (hc0)
  if (tid < E){
    const float* wx = W_xctx + (size_t)tid*(E+H) + E + hc*64;
    float acc = 0.0f;
    #pragma unroll
    for (int k=0;k<64;k+=4){
      const float4 w = *reinterpret_cast<const float4*>(wx+k);
      acc += sctx[k]*w.x + sctx[k+1]*w.y + sctx[k+2]*w.z + sctx[k+3]*w.w;
    }
    if (hc==0){
      const float* we = W_xctx + (size_t)tid*(E+H);
      #pragma unroll 8
      for (int k=0;k<E;k+=4){
        const float4 w = *reinterpret_cast<const float4*>(we+k);
        acc += se[k]*w.x + se[k+1]*w.y + se[k+2]*w.z + se[k+3]*w.w;
      }
      acc += b_xctx[tid];
    }
    atomicAdd(&xnext[b*E + tid], acc);
  }
  // pgen: ctx-part (all hc) + h/x parts & bias (hc0)
  {
    float part = (tid < 64) ? sctx[tid]*W_pgen[hc*64 + tid] : 0.0f;
    if (hc==0){
      for (int k=tid;k<H;k+=256) part += shh[k]*W_pgen[H + k];
      for (int k=tid;k<E;k+=256) part += xcur[b*E + k]*W_pgen[2*H + k];
    }
    __syncthreads();
    red[tid] = part;
    __syncthreads();
    for (int off=128; off>0; off>>=1){ if (tid<off) red[tid]+=red[tid+off]; __syncthreads(); }
    if (tid==0) atomicAdd(&praw_t[b], red[0] + (hc==0 ? b_pgen[0] : 0.0f));
  }
}

// Batched vocab GEMM chunk: 4 steps (64 rows). grid (125, 2) x 256.
// es[r][v] = exp(hh_row_r . W_vocab[v] + b_vocab[v]);  vsum[row] += partials.
__global__ __launch_bounds__(256) void k_vocab(const float* __restrict__ hh_all,
    const float* __restrict__ W_vocab, const float* __restrict__ b_vocab,
    float* __restrict__ es, float* __restrict__ vsum, int t0){
  __shared__ float shh[32][H];
  const int tid = threadIdx.x;
  const int m0 = blockIdx.y*32;
  const float* src = hh_all + ((size_t)t0*B + m0)*H;
  for (int i=tid; i<32*(H/4); i+=256)
    reinterpret_cast<float4*>(&shh[0][0])[i] = reinterpret_cast<const float4*>(src)[i];
  __syncthreads();
  const int v = blockIdx.x*256 + tid;
  const float* wr = W_vocab + (size_t)v*H;
  float acc[32];
  #pragma unroll
  for (int m=0;m<32;++m) acc[m]=0.0f;
  for (int k=0;k<H;k+=4){
    const float4 w = *reinterpret_cast<const float4*>(wr + k);
    #pragma unroll
    for (int m=0;m<32;++m){
      const float4 hv = *reinterpret_cast<const float4*>(&shh[m][k]);
      acc[m] += hv.x*w.x + hv.y*w.y + hv.z*w.z + hv.w*w.w;
    }
  }
  const float bv = b_vocab[v];
  const int lane = tid & 63;
  #pragma unroll
  for (int m=0;m<32;++m){
    const float e = __expf(acc[m] + bv);
    es[(size_t)(m0 + m)*V + v] = e;
    float s = e;
    #pragma unroll
    for (int off=32; off>0; off>>=1) s += __shfl_down(s, off);
    if (lane==0) atomicAdd(&vsum[t0*B + m0 + m], s);
  }
}

// grid (64 rows, 33 vc) x 256: out = es * pg/vsum; OOV tail.
__global__ __launch_bounds__(256) void k_finalize(const float* __restrict__ es,
    const float* __restrict__ praw, const float* __restrict__ vsum,
    const float* __restrict__ exz, float* __restrict__ out, int t0){
  const int r = blockIdx.x, vc = blockIdx.y, tid = threadIdx.x;
  const int gr = t0*B + r;
  const int t = gr >> 4, b = gr & 15;
  float* orow = out + ((size_t)b*T + t)*VEXT;
  if (vc < 32){
    const float scl = fsig(praw[gr]) / vsum[gr];
    const float* e = es + (size_t)r*V + vc*1000;
    for (int i=tid; i<1000; i+=256) orow[vc*1000 + i] = e[i]*scl;
  } else if (tid < OOV){
    orow[V + tid] = exz[b*OOV + tid];
  }
}

// grid 200 x 256, grid-stride: scatter copy-dist for ALL steps.
__global__ __launch_bounds__(256) void k_scatter_all(const float* __restrict__ probs_all,
    const float* __restrict__ praw, const int* __restrict__ eidx,
    float* __restrict__ out){
  const int stride = gridDim.x*256;
  for (int i = blockIdx.x*256 + threadIdx.x; i < T*B*S; i += stride){
    const int t = i / (B*S);
    const int rem = i - t*B*S;
    const int b = rem / S, s = rem - b*S;
    const float fac = 1.0f - fsig(praw[t*B + b]);
    float* orow = out + ((size_t)b*T + t)*VEXT;
    atomicAdd(&orow[eidx[b*S + s]], fac*probs_all[(size_t)(t*B + b)*S + s]);
  }
}

} // namespace

extern "C" void kernel_launch(void* const* d_in, const int* in_sizes, int n_in,
                              void* d_out, int out_size, void* d_ws, size_t ws_size,
                              hipStream_t stream){
  const float* emb    = (const float*)d_in[0];
  const float* h0     = (const float*)d_in[1];
  const float* c0     = (const float*)d_in[2];
  const float* enc    = (const float*)d_in[3];
  const float* masks  = (const float*)d_in[4];
  const float* exz    = (const float*)d_in[5];
  const int*   eidx   = (const int*)d_in[6];
  const float* W_ih   = (const float*)d_in[7];
  const float* W_hh   = (const float*)d_in[8];
  const float* b_ih   = (const float*)d_in[9];
  const float* b_hh   = (const float*)d_in[10];
  const float* W_vocab= (const float*)d_in[11];
  const float* b_vocab= (const float*)d_in[12];
  const float* W_cov  = (const float*)d_in[13];
  const float* W_energy=(const float*)d_in[14];
  const float* b_energy=(const float*)d_in[15];
  const float* v_attn = (const float*)d_in[16];
  const float* W_xctx = (const float*)d_in[17];
  const float* b_xctx = (const float*)d_in[18];
  const float* W_ad   = (const float*)d_in[19];
  const float* b_ad   = (const float*)d_in[20];
  const float* W_pgen = (const float*)d_in[21];
  const float* b_pgen = (const float*)d_in[22];

  float* ws = (float*)d_ws;
  float* hbuf   = ws;               // 2 x 8192
  float* cbuf   = ws + 16384;       // 2 x 8192
  float* xbuf   = ws + 32768;       // 2 x 2048
  float* score  = ws + 36864;       // 6400
  float* cov    = ws + 43264;       // 6400
  float* praw   = ws + 49664;       // 512
  float* vsum   = ws + 50176;       // 512
  float* probs_all = ws + 50688;    // 204800
  float* hh_all = ws + 255488;      // 262144
  float* es     = ws + 517632;      // 2048000
  float* encp   = ws + 2565632;     // 3276800
  float* Wt     = es;               // 262144, aliased (setup-only)
  float* outp   = (float*)d_out;

  k_init<<<300,256,0,stream>>>(h0,c0,hbuf,cbuf,cov,praw,vsum,hh_all);
  k_x0<<<16,128,0,stream>>>(emb,W_xctx,b_xctx,xbuf);
  k_trw<<<dim3(16,16),256,0,stream>>>(W_energy,Wt);
  k_encproj<<<400,512,0,stream>>>(enc,Wt,b_energy,encp);

  for (int t=0;t<T;++t){
    const int p = t&1;
    const float* hold = hbuf + p*8192;
    const float* cold = cbuf + p*8192;
    float* hnew = hbuf + (p^1)*8192;
    float* cnew = cbuf + (p^1)*8192;
    const float* xcur = xbuf + p*2048;
    float* xnext = xbuf + (p^1)*2048;
    const int tnext = (t+1 < T) ? (t+1) : (T-1);
    k_gates<<<64,256,0,stream>>>(xcur,hold,cold,W_ih,W_hh,b_ih,b_hh,hnew,cnew);
    k_decscore<<<16,1024,0,stream>>>(hnew,W_energy,encp,W_cov,v_attn,cov,score,xnext);
    k_ctxpost<<<dim3(16,8),256,0,stream>>>(score,masks,enc,hnew,xcur,emb,tnext,
        W_ad,b_ad,W_pgen,b_pgen,W_xctx,b_xctx,
        cov,probs_all + (size_t)t*B*S, hh_all + (size_t)t*B*H, praw + t*B, xnext);
  }

  for (int t0=0; t0<T; t0+=4){
    k_vocab<<<dim3(125,2),256,0,stream>>>(hh_all,W_vocab,b_vocab,es,vsum,t0);
    k_finalize<<<dim3(64,33),256,0,stream>>>(es,praw,vsum,exz,outp,t0);
  }
  k_scatter_all<<<200,256,0,stream>>>(probs_all,praw,eidx,outp);
}

// Round 5
// 5240.985 us; speedup vs baseline: 1.3761x; 1.3761x over previous
//
#include <hip/hip_runtime.h>
#include <hip/hip_bf16.h>
#include <hip/hip_cooperative_groups.h>
#include <cstddef>

namespace cg = cooperative_groups;

namespace {

constexpr int B = 16, T = 32, S = 400, E = 128, H = 512, V = 32000, OOV = 50, VEXT = V + OOV;

typedef __attribute__((ext_vector_type(8))) short short8v;
typedef __attribute__((ext_vector_type(4))) float f32x4;

__device__ __forceinline__ float fsig(float x){ return 1.0f/(1.0f+__expf(-x)); }
__device__ __forceinline__ float ftanh(float x){
  float ax = fabsf(x);
  float t = __expf(-2.0f*ax);
  float r = (1.0f - t)/(1.0f + t);
  return copysignf(r, x);
}
__device__ __forceinline__ unsigned short f2bf(float f){   // round-to-nearest-even
  unsigned int u = __float_as_uint(f);
  unsigned int r = (u + 0x7FFFu + ((u >> 16) & 1u)) >> 16;
  return (unsigned short)r;
}

__global__ __launch_bounds__(256) void k_init(const float* __restrict__ h0, const float* __restrict__ c0,
    float* __restrict__ h, float* __restrict__ c, float* __restrict__ cov,
    float* __restrict__ praw, float* __restrict__ vsum){
  int i = blockIdx.x*256 + threadIdx.x;
  if (i < B*H){ h[i]=h0[i]; c[i]=c0[i]; }
  if (i < B*S) cov[i]=0.0f;
  if (i < T*B){ praw[i]=0.0f; vsum[i]=0.0f; }
}

// x0[b][j] = emb[b][0][:] . W_xctx[j][:E] + b_xctx[j]   (ctx_0 = 0)
__global__ __launch_bounds__(128) void k_x0(const float* __restrict__ emb,
    const float* __restrict__ W_xctx, const float* __restrict__ b_xctx,
    float* __restrict__ x0){
  const int b = blockIdx.x, tid = threadIdx.x;
  __shared__ float se[E];
  se[tid] = emb[(size_t)(b*T)*E + tid];
  __syncthreads();
  const float* w = W_xctx + (size_t)tid*(E+H);
  float acc = b_xctx[tid];
  #pragma unroll 8
  for (int k=0;k<E;k+=4){
    float4 wv = *reinterpret_cast<const float4*>(w+k);
    acc += se[k]*wv.x + se[k+1]*wv.y + se[k+2]*wv.z + se[k+3]*wv.w;
  }
  x0[b*E + tid] = acc;
}

// OUT[a][b] = W_energy[b][off+a], a,b in [0,512). grid (16,16) x 256.
__global__ __launch_bounds__(256) void k_trw(const float* __restrict__ W_energy,
                                             float* __restrict__ out, int off){
  __shared__ float tile[32][33];
  const int j0 = blockIdx.x*32, k0 = blockIdx.y*32;
  const int tx = threadIdx.x & 31, ty = threadIdx.x >> 5;
  #pragma unroll
  for (int r=0;r<4;++r)
    tile[ty+8*r][tx] = W_energy[(size_t)(k0+ty+8*r)*(2*H) + off + j0 + tx];
  __syncthreads();
  #pragma unroll
  for (int r=0;r<4;++r)
    out[(size_t)(j0+ty+8*r)*H + k0 + tx] = tile[tx][ty+8*r];
}

// enc_proj: 400 blocks x 512 threads; 16 s-rows register-blocked x 512 k.
__global__ __launch_bounds__(512) void k_encproj(const float* __restrict__ enc,
                          const float* __restrict__ Wt,
                          const float* __restrict__ b_energy,
                          float* __restrict__ enc_proj){
  __shared__ float ldsE[16][H];
  const int r0 = blockIdx.x * 16;
  const int tid = threadIdx.x;
  for (int i = tid; i < 16*(H/4); i += 512){
    const int r = i >> 7, cc = i & 127;
    *reinterpret_cast<float4*>(&ldsE[r][cc*4]) =
        *reinterpret_cast<const float4*>(&enc[(size_t)(r0+r)*H + cc*4]);
  }
  __syncthreads();
  const int k = tid;
  float acc[16];
  #pragma unroll
  for (int r=0;r<16;++r) acc[r]=0.0f;
  #pragma unroll 2
  for (int j=0;j<H;j+=4){
    const float w0 = Wt[(size_t) j   *H + k];
    const float w1 = Wt[(size_t)(j+1)*H + k];
    const float w2 = Wt[(size_t)(j+2)*H + k];
    const float w3 = Wt[(size_t)(j+3)*H + k];
    #pragma unroll
    for (int r=0;r<16;++r){
      const float4 e = *reinterpret_cast<const float4*>(&ldsE[r][j]);
      acc[r] += e.x*w0 + e.y*w1 + e.z*w2 + e.w*w3;
    }
  }
  const float be = b_energy[k];
  #pragma unroll
  for (int r=0;r<16;++r) enc_proj[(size_t)(r0+r)*H + k] = acc[r] + be;
}

struct LP {
  const float *emb, *enc, *masks;
  const float *W_ih, *W_hh, *b_ih, *b_hh;
  const float *W_cov, *W_energy, *v_attn;
  const float *W_xctx, *b_xctx, *W_ad, *b_ad, *W_pgen, *b_pgen;
  float *hbuf, *cbuf, *xbuf, *dec, *score, *cov, *praw, *probs_all, *hh_all;
  const float *WdT, *encp;
  unsigned short *hh_bf;
};

// Cooperative kernel: whole T-loop. 128 blocks x 256 threads.
__global__ __launch_bounds__(256, 1) void fused_loop(LP P){
  cg::grid_group gg = cg::this_grid();
  const int blk = blockIdx.x, tid = threadIdx.x;
  __shared__ union {
    struct { float xh[8][640]; float sg[4][64][9]; } A;
    struct { float sdec[H]; float swc[H]; float sva[H]; float r2[4][64]; } Bp;
    struct { float red[256]; float sp[512]; float sctx[64]; float shh[H]; float se[E]; } C;
  } sm;

  // zero hh_all (its region doubled as Wt scratch during setup)
  for (int i = blk*256 + tid; i < T*B*H; i += 128*256) P.hh_all[i] = 0.0f;
  gg.sync();

  for (int t=0; t<T; ++t){
    const int p = t&1;
    const float* hold = P.hbuf + p*8192;        float* hnew = P.hbuf + (p^1)*8192;
    const float* cold = P.cbuf + p*8192;        float* cnew = P.cbuf + (p^1)*8192;
    const float* xcur = P.xbuf + p*2048;        float* xnext = P.xbuf + (p^1)*2048;
    const int tnext = (t+1 < T) ? (t+1) : (T-1);

    // ---- Phase A: gates GEMM + LSTM (blocks 0..63) ----
    if (blk < 64){
      const int gb = blk >> 1, bh = blk & 1, b0 = bh*8;
      for (int b=0;b<8;++b)
        for (int k=tid;k<640;k+=256)
          sm.A.xh[b][k] = (k<E) ? xcur[(b0+b)*E + k] : hold[(b0+b)*H + (k-E)];
      __syncthreads();
      const int w = tid >> 6, l = tid & 63, g = l >> 4, jj = l & 15;
      const int row = g*H + gb*16 + jj;
      float acc[8];
      #pragma unroll
      for (int b=0;b<8;++b) acc[b]=0.0f;
      const int ks = w*160, ke = ks + 160;
      if (ks < 128){
        const float* wr = P.W_ih + (size_t)row*E;
        for (int k=0;k<128;k+=4){
          const float4 wv = *reinterpret_cast<const float4*>(wr + k);
          #pragma unroll
          for (int b=0;b<8;++b){
            const float4 xv = *reinterpret_cast<const float4*>(&sm.A.xh[b][k]);
            acc[b] += xv.x*wv.x + xv.y*wv.y + xv.z*wv.z + xv.w*wv.w;
          }
        }
      }
      {
        const int hs = (ks < 128) ? 128 : ks;
        const float* wr = P.W_hh + (size_t)row*H - 128;
        for (int k=hs;k<ke;k+=4){
          const float4 wv = *reinterpret_cast<const float4*>(wr + k);
          #pragma unroll
          for (int b=0;b<8;++b){
            const float4 xv = *reinterpret_cast<const float4*>(&sm.A.xh[b][k]);
            acc[b] += xv.x*wv.x + xv.y*wv.y + xv.z*wv.z + xv.w*wv.w;
          }
        }
      }
      #pragma unroll
      for (int b=0;b<8;++b) sm.A.sg[w][l][b] = acc[b];
      __syncthreads();
      if (tid < 128){
        const int b = tid >> 4, j2 = tid & 15;
        float gs[4];
        #pragma unroll
        for (int g2=0;g2<4;++g2){
          const int ll = g2*16 + j2;
          const int rw = g2*H + gb*16 + j2;
          gs[g2] = sm.A.sg[0][ll][b]+sm.A.sg[1][ll][b]+sm.A.sg[2][ll][b]+sm.A.sg[3][ll][b]
                   + P.b_ih[rw] + P.b_hh[rw];
        }
        const float ig = fsig(gs[0]);
        const float fg = fsig(gs[1]);
        const float g3 = ftanh(gs[2]);
        const float og = fsig(gs[3]);
        const int idx = (b0+b)*H + gb*16 + j2;
        const float cn = fg*cold[idx] + ig*g3;
        cnew[idx] = cn;
        hnew[idx] = og*ftanh(cn);
      }
    }
    gg.sync();

    // ---- Phase B1: dec GEMV (coalesced via WdT) + zero xnext ----
    {
      const int b = blk >> 3, jc = blk & 7;
      const int jl = tid & 63, kq = tid >> 6;
      const int j = jc*64 + jl;
      float acc = 0.0f;
      for (int k = kq*128; k < kq*128+128; ++k)
        acc += hnew[b*H + k] * P.WdT[(size_t)k*H + j];
      sm.Bp.r2[kq][jl] = acc;
      if (jc==0 && tid < E) xnext[b*E + tid] = 0.0f;
      __syncthreads();
      if (tid < 64)
        P.dec[b*H + jc*64 + tid] = sm.Bp.r2[0][tid]+sm.Bp.r2[1][tid]+sm.Bp.r2[2][tid]+sm.Bp.r2[3][tid];
    }
    gg.sync();

    // ---- Phase B2: attention scores (50 s per block) ----
    {
      const int b = blk >> 3, s0 = (blk & 7)*50;
      for (int i=tid;i<H;i+=256){
        sm.Bp.sdec[i] = P.dec[b*H + i];
        sm.Bp.swc[i]  = P.W_cov[i];
        sm.Bp.sva[i]  = P.v_attn[i];
      }
      __syncthreads();
      const int wid = tid >> 6, lane = tid & 63, k0 = lane*8;
      for (int s = s0 + wid; s < s0 + 50; s += 4){
        const float cv = P.cov[b*S + s];
        const float* ep = P.encp + (size_t)(b*S+s)*H + k0;
        float a = 0.0f;
        #pragma unroll
        for (int u=0;u<8;++u)
          a += ftanh(sm.Bp.sdec[k0+u] + ep[u] + cv*sm.Bp.swc[k0+u]) * sm.Bp.sva[k0+u];
        #pragma unroll
        for (int off=32; off>0; off>>=1) a += __shfl_down(a, off);
        if (lane==0) P.score[b*S + s] = a;
      }
    }
    gg.sync();

    // ---- Phase C: softmax + ctx + hh/xnext/pgen assembly ----
    {
      const int b = blk >> 3, hc = blk & 7;
      float* probs_t = P.probs_all + (size_t)t*B*S;
      float* hh_t    = P.hh_all    + (size_t)t*B*H;
      float* praw_t  = P.praw + t*B;
      if (hc==0){
        for (int i=tid;i<H;i+=256) sm.C.shh[i] = hnew[b*H + i];
        if (tid < E) sm.C.se[tid] = P.emb[(size_t)(b*T + tnext)*E + tid];
      }
      const float sc0 = (tid < S)      ? P.score[b*S + tid]       : -1e30f;
      const float sc1 = (tid+256 < S)  ? P.score[b*S + tid + 256] : -1e30f;
      sm.C.red[tid] = fmaxf(sc0, sc1);
      __syncthreads();
      for (int off=128; off>0; off>>=1){ if (tid<off) sm.C.red[tid]=fmaxf(sm.C.red[tid],sm.C.red[tid+off]); __syncthreads(); }
      const float mx = sm.C.red[0];
      __syncthreads();
      const float e0 = (tid < S)     ? __expf(sc0 - mx) : 0.0f;
      const float e1 = (tid+256 < S) ? __expf(sc1 - mx) : 0.0f;
      sm.C.red[tid] = e0 + e1;
      __syncthreads();
      for (int off=128; off>0; off>>=1){ if (tid<off) sm.C.red[tid]+=sm.C.red[tid+off]; __syncthreads(); }
      const float den = sm.C.red[0];
      __syncthreads();
      const float p0 = (tid < S)     ? (e0/den)*P.masks[b*S+tid]     : 0.0f;
      const float p1 = (tid+256 < S) ? (e1/den)*P.masks[b*S+tid+256] : 0.0f;
      sm.C.red[tid] = p0 + p1;
      __syncthreads();
      for (int off=128; off>0; off>>=1){ if (tid<off) sm.C.red[tid]+=sm.C.red[tid+off]; __syncthreads(); }
      const float inv = 1.0f/(sm.C.red[0] + 1e-12f);
      __syncthreads();
      const float pr0 = p0*inv, pr1 = p1*inv;
      sm.C.sp[tid] = pr0; sm.C.sp[tid+256] = pr1;
      if (hc==0){
        if (tid < S){ probs_t[b*S+tid] = pr0; P.cov[b*S+tid] += pr0; }
        if (tid+256 < S){ probs_t[b*S+tid+256] = pr1; P.cov[b*S+tid+256] += pr1; }
      }
      __syncthreads();
      {
        const int c = tid & 63, sg_ = tid >> 6;
        const float* eb = P.enc + (size_t)b*S*H + hc*64 + c;
        float a = 0.0f;
        for (int s=sg_; s<S; s+=4) a += sm.C.sp[s]*eb[(size_t)s*H];
        sm.C.red[tid] = a;
        __syncthreads();
        if (tid < 64) sm.C.sctx[tid] = sm.C.red[tid]+sm.C.red[tid+64]+sm.C.red[tid+128]+sm.C.red[tid+192];
      }
      __syncthreads();
      for (int j=tid; j<H; j+=256){
        const float* wa = P.W_ad + (size_t)j*(2*H) + H + hc*64;
        float acc = 0.0f;
        #pragma unroll
        for (int k=0;k<64;k+=4){
          const float4 w = *reinterpret_cast<const float4*>(wa+k);
          acc += sm.C.sctx[k]*w.x + sm.C.sctx[k+1]*w.y + sm.C.sctx[k+2]*w.z + sm.C.sctx[k+3]*w.w;
        }
        if (hc==0){
          const float* wh = P.W_ad + (size_t)j*(2*H);
          #pragma unroll 8
          for (int k=0;k<H;k+=4){
            const float4 w = *reinterpret_cast<const float4*>(wh+k);
            acc += sm.C.shh[k]*w.x + sm.C.shh[k+1]*w.y + sm.C.shh[k+2]*w.z + sm.C.shh[k+3]*w.w;
          }
          acc += P.b_ad[j];
        }
        atomicAdd(&hh_t[b*H + j], acc);
      }
      if (tid < E){
        const float* wx = P.W_xctx + (size_t)tid*(E+H) + E + hc*64;
        float acc = 0.0f;
        #pragma unroll
        for (int k=0;k<64;k+=4){
          const float4 w = *reinterpret_cast<const float4*>(wx+k);
          acc += sm.C.sctx[k]*w.x + sm.C.sctx[k+1]*w.y + sm.C.sctx[k+2]*w.z + sm.C.sctx[k+3]*w.w;
        }
        if (hc==0){
          const float* we = P.W_xctx + (size_t)tid*(E+H);
          #pragma unroll 8
          for (int k=0;k<E;k+=4){
            const float4 w = *reinterpret_cast<const float4*>(we+k);
            acc += sm.C.se[k]*w.x + sm.C.se[k+1]*w.y + sm.C.se[k+2]*w.z + sm.C.se[k+3]*w.w;
          }
          acc += P.b_xctx[tid];
        }
        atomicAdd(&xnext[b*E + tid], acc);
      }
      {
        float part = (tid < 64) ? sm.C.sctx[tid]*P.W_pgen[hc*64 + tid] : 0.0f;
        if (hc==0){
          for (int k=tid;k<H;k+=256) part += sm.C.shh[k]*P.W_pgen[H + k];
          for (int k=tid;k<E;k+=256) part += xcur[b*E + k]*P.W_pgen[2*H + k];
        }
        __syncthreads();
        sm.C.red[tid] = part;
        __syncthreads();
        for (int off=128; off>0; off>>=1){ if (tid<off) sm.C.red[tid]+=sm.C.red[tid+off]; __syncthreads(); }
        if (tid==0) atomicAdd(&praw_t[b], sm.C.red[0] + (hc==0 ? P.b_pgen[0] : 0.0f));
      }
    }
    gg.sync();
  }

  // convert hh_all -> bf16 for the MFMA vocab GEMM
  for (int i = blk*256 + tid; i < T*B*H; i += 128*256)
    P.hh_bf[i] = f2bf(P.hh_all[i]);
}

// MFMA vocab GEMM: es = exp(hh_bf . W_vocab^T + b_vocab) written straight into out;
// row sums accumulated into vsum. Grid 250 x 256 (4 waves, 32 n per wave, all M=512).
__global__ __launch_bounds__(256) void k_vocab_mfma(
    const unsigned short* __restrict__ hh_bf,
    const float* __restrict__ W_vocab, const float* __restrict__ b_vocab,
    float* __restrict__ out, float* __restrict__ vsum){
  const int tid = threadIdx.x, lane = tid & 63, w = tid >> 6;
  const int nl = lane & 15, kg = lane >> 4;
  const int nbase = blockIdx.x*128 + w*32;
  const int n0 = nbase + nl, n1 = nbase + 16 + nl;
  __shared__ float svs[512];
  for (int i=tid;i<512;i+=256) svs[i]=0.0f;
  __syncthreads();
  const float bv0 = b_vocab[n0], bv1 = b_vocab[n1];
  const float* wr0 = W_vocab + (size_t)n0*H;
  const float* wr1 = W_vocab + (size_t)n1*H;
  for (int mc=0; mc<4; ++mc){
    f32x4 acc0[8], acc1[8];
    #pragma unroll
    for (int mf=0;mf<8;++mf){
      acc0[mf] = (f32x4){0.f,0.f,0.f,0.f};
      acc1[mf] = (f32x4){0.f,0.f,0.f,0.f};
    }
    for (int kk=0; kk<16; ++kk){
      const int ko = kk*32 + kg*8;
      short8v bf0, bf1;
      const float4 wa0 = *reinterpret_cast<const float4*>(wr0 + ko);
      const float4 wb0 = *reinterpret_cast<const float4*>(wr0 + ko + 4);
      const float4 wa1 = *reinterpret_cast<const float4*>(wr1 + ko);
      const float4 wb1 = *reinterpret_cast<const float4*>(wr1 + ko + 4);
      bf0[0]=(short)f2bf(wa0.x); bf0[1]=(short)f2bf(wa0.y); bf0[2]=(short)f2bf(wa0.z); bf0[3]=(short)f2bf(wa0.w);
      bf0[4]=(short)f2bf(wb0.x); bf0[5]=(short)f2bf(wb0.y); bf0[6]=(short)f2bf(wb0.z); bf0[7]=(short)f2bf(wb0.w);
      bf1[0]=(short)f2bf(wa1.x); bf1[1]=(short)f2bf(wa1.y); bf1[2]=(short)f2bf(wa1.z); bf1[3]=(short)f2bf(wa1.w);
      bf1[4]=(short)f2bf(wb1.x); bf1[5]=(short)f2bf(wb1.y); bf1[6]=(short)f2bf(wb1.z); bf1[7]=(short)f2bf(wb1.w);
      #pragma unroll
      for (int mf=0;mf<8;++mf){
        const int m = mc*128 + mf*16 + nl;
        const short8v af = *reinterpret_cast<const short8v*>(hh_bf + (size_t)m*H + ko);
        acc0[mf] = __builtin_amdgcn_mfma_f32_16x16x32_bf16(af, bf0, acc0[mf], 0, 0, 0);
        acc1[mf] = __builtin_amdgcn_mfma_f32_16x16x32_bf16(af, bf1, acc1[mf], 0, 0, 0);
      }
    }
    #pragma unroll
    for (int mf=0;mf<8;++mf){
      #pragma unroll
      for (int r=0;r<4;++r){
        const int m = mc*128 + mf*16 + kg*4 + r;   // m = t*16 + b
        const int tq = m >> 4, bq = m & 15;
        const float e0 = __expf(acc0[mf][r] + bv0);
        const float e1 = __expf(acc1[mf][r] + bv1);
        float* orow = out + ((size_t)bq*T + tq)*VEXT;
        orow[n0] = e0;
        orow[n1] = e1;
        float s = e0 + e1;
        #pragma unroll
        for (int off=1; off<16; off<<=1) s += __shfl_xor(s, off);
        if (nl==0) atomicAdd(&svs[m], s);
      }
    }
  }
  __syncthreads();
  for (int i=tid;i<512;i+=256) atomicAdd(&vsum[i], svs[i]);
}

// scale out rows in place + OOV tail. grid (512 rows, 9) x 256.
__global__ __launch_bounds__(256) void k_finalize(const float* __restrict__ praw,
    const float* __restrict__ vsum, const float* __restrict__ exz,
    float* __restrict__ out){
  const int rm = blockIdx.x, vc = blockIdx.y, tid = threadIdx.x;
  const int t = rm >> 4, b = rm & 15;
  float* orow = out + ((size_t)b*T + t)*VEXT;
  if (vc < 8){
    const float scl = fsig(praw[rm]) / vsum[rm];
    const int base = vc*4000;
    for (int i = tid; i < 4000; i += 256) orow[base + i] *= scl;
  } else if (tid < OOV){
    orow[V + tid] = exz[b*OOV + tid];
  }
}

// grid-stride scatter of copy-dist for all steps.
__global__ __launch_bounds__(256) void k_scatter_all(const float* __restrict__ probs_all,
    const float* __restrict__ praw, const int* __restrict__ eidx,
    float* __restrict__ out){
  const int stride = gridDim.x*256;
  for (int i = blockIdx.x*256 + threadIdx.x; i < T*B*S; i += stride){
    const int t = i / (B*S);
    const int rem = i - t*B*S;
    const int b = rem / S, s = rem - b*S;
    const float fac = 1.0f - fsig(praw[t*B + b]);
    float* orow = out + ((size_t)b*T + t)*VEXT;
    atomicAdd(&orow[eidx[b*S + s]], fac*probs_all[(size_t)(t*B + b)*S + s]);
  }
}

} // namespace

extern "C" void kernel_launch(void* const* d_in, const int* in_sizes, int n_in,
                              void* d_out, int out_size, void* d_ws, size_t ws_size,
                              hipStream_t stream){
  const float* emb    = (const float*)d_in[0];
  const float* h0     = (const float*)d_in[1];
  const float* c0     = (const float*)d_in[2];
  const float* enc    = (const float*)d_in[3];
  const float* masks  = (const float*)d_in[4];
  const float* exz    = (const float*)d_in[5];
  const int*   eidx   = (const int*)d_in[6];
  const float* W_ih   = (const float*)d_in[7];
  const float* W_hh   = (const float*)d_in[8];
  const float* b_ih   = (const float*)d_in[9];
  const float* b_hh   = (const float*)d_in[10];
  const float* W_vocab= (const float*)d_in[11];
  const float* b_vocab= (const float*)d_in[12];
  const float* W_cov  = (const float*)d_in[13];
  const float* W_energy=(const float*)d_in[14];
  const float* b_energy=(const float*)d_in[15];
  const float* v_attn = (const float*)d_in[16];
  const float* W_xctx = (const float*)d_in[17];
  const float* b_xctx = (const float*)d_in[18];
  const float* W_ad   = (const float*)d_in[19];
  const float* b_ad   = (const float*)d_in[20];
  const float* W_pgen = (const float*)d_in[21];
  const float* b_pgen = (const float*)d_in[22];

  float* ws = (float*)d_ws;
  float* hbuf     = ws;                 // 2 x 8192
  float* cbuf     = ws + 16384;         // 2 x 8192
  float* xbuf     = ws + 32768;         // 2 x 2048
  float* dec      = ws + 36864;         // 8192
  float* score    = ws + 45056;         // 6400
  float* cov      = ws + 51456;         // 6400
  float* praw     = ws + 57856;         // 512
  float* vsum     = ws + 58368;         // 512
  float* probs_all= ws + 58880;         // 204800
  float* hh_all   = ws + 263680;        // 262144  (doubles as Wt scratch pre-loop)
  float* WdT      = ws + 525824;        // 262144
  float* hh_bf_f  = ws + 787968;        // 131072 floats = 262144 ushort
  float* encp     = ws + 919040;        // 3276800
  unsigned short* hh_bf = (unsigned short*)hh_bf_f;
  float* Wt       = hh_all;             // alias: used only before fused_loop zeroes it
  float* outp     = (float*)d_out;

  k_init<<<32,256,0,stream>>>(h0,c0,hbuf,cbuf,cov,praw,vsum);
  k_x0<<<16,128,0,stream>>>(emb,W_xctx,b_xctx,xbuf);
  k_trw<<<dim3(16,16),256,0,stream>>>(W_energy,Wt,H);    // W_e^T for encproj
  k_trw<<<dim3(16,16),256,0,stream>>>(W_energy,WdT,0);   // W_d^T for dec GEMV
  k_encproj<<<400,512,0,stream>>>(enc,Wt,b_energy,encp);

  LP P;
  P.emb=emb; P.enc=enc; P.masks=masks;
  P.W_ih=W_ih; P.W_hh=W_hh; P.b_ih=b_ih; P.b_hh=b_hh;
  P.W_cov=W_cov; P.W_energy=W_energy; P.v_attn=v_attn;
  P.W_xctx=W_xctx; P.b_xctx=b_xctx; P.W_ad=W_ad; P.b_ad=b_ad;
  P.W_pgen=W_pgen; P.b_pgen=b_pgen;
  P.hbuf=hbuf; P.cbuf=cbuf; P.xbuf=xbuf; P.dec=dec; P.score=score; P.cov=cov;
  P.praw=praw; P.probs_all=probs_all; P.hh_all=hh_all;
  P.WdT=WdT; P.encp=encp; P.hh_bf=hh_bf;
  void* args[] = { (void*)&P };
  hipLaunchCooperativeKernel((const void*)fused_loop, dim3(128), dim3(256), args, 0, stream);

  k_vocab_mfma<<<250,256,0,stream>>>(hh_bf,W_vocab,b_vocab,outp,vsum);
  k_finalize<<<dim3(512,9),256,0,stream>>>(praw,vsum,exz,outp);
  k_scatter_all<<<200,256,0,stream>>>(probs_all,praw,eidx,outp);
}

// Round 6
// 3575.336 us; speedup vs baseline: 2.0172x; 1.4659x over previous
//
#include <hip/hip_runtime.h>
#include <hip/hip_bf16.h>
#include <cstddef>

namespace {

constexpr int B = 16, T = 32, S = 400, E = 128, H = 512, V = 32000, OOV = 50, VEXT = V + OOV;

typedef __attribute__((ext_vector_type(8))) short short8v;
typedef __attribute__((ext_vector_type(4))) float f32x4;

__device__ __forceinline__ float fsig(float x){ return 1.0f/(1.0f+__expf(-x)); }
__device__ __forceinline__ float ftanh(float x){
  float ax = fabsf(x);
  float t = __expf(-2.0f*ax);
  float r = (1.0f - t)/(1.0f + t);
  return copysignf(r, x);
}
__device__ __forceinline__ unsigned short f2bf(float f){   // round-to-nearest-even
  unsigned int u = __float_as_uint(f);
  unsigned int r = (u + 0x7FFFu + ((u >> 16) & 1u)) >> 16;
  return (unsigned short)r;
}

// grid-stride init: copy h0/c0, zero cov, praw, vsum, hh_all.
__global__ __launch_bounds__(256) void k_init(const float* __restrict__ h0, const float* __restrict__ c0,
    float* __restrict__ h, float* __restrict__ c, float* __restrict__ cov,
    float* __restrict__ praw, float* __restrict__ vsum, float* __restrict__ hh_all){
  const int stride = gridDim.x*256;
  for (int i = blockIdx.x*256 + threadIdx.x; i < T*B*H; i += stride){
    hh_all[i] = 0.0f;
    if (i < B*H){ h[i]=h0[i]; c[i]=c0[i]; }
    if (i < B*S) cov[i]=0.0f;
    if (i < T*B){ praw[i]=0.0f; vsum[i]=0.0f; }
  }
}

// x0[b][j] = emb[b][0][:] . W_xctx[j][:E] + b_xctx[j]   (ctx_0 = 0)
__global__ __launch_bounds__(128) void k_x0(const float* __restrict__ emb,
    const float* __restrict__ W_xctx, const float* __restrict__ b_xctx,
    float* __restrict__ x0){
  const int b = blockIdx.x, tid = threadIdx.x;
  __shared__ float se[E];
  se[tid] = emb[(size_t)(b*T)*E + tid];
  __syncthreads();
  const float* w = W_xctx + (size_t)tid*(E+H);
  float acc = b_xctx[tid];
  #pragma unroll 8
  for (int k=0;k<E;k+=4){
    float4 wv = *reinterpret_cast<const float4*>(w+k);
    acc += se[k]*wv.x + se[k+1]*wv.y + se[k+2]*wv.z + se[k+3]*wv.w;
  }
  x0[b*E + tid] = acc;
}

// OUT[a][b] = W_energy[b][off+a], a,b in [0,512). grid (16,16) x 256.
__global__ __launch_bounds__(256) void k_trw(const float* __restrict__ W_energy,
                                             float* __restrict__ out, int off){
  __shared__ float tile[32][33];
  const int j0 = blockIdx.x*32, k0 = blockIdx.y*32;
  const int tx = threadIdx.x & 31, ty = threadIdx.x >> 5;
  #pragma unroll
  for (int r=0;r<4;++r)
    tile[ty+8*r][tx] = W_energy[(size_t)(k0+ty+8*r)*(2*H) + off + j0 + tx];
  __syncthreads();
  #pragma unroll
  for (int r=0;r<4;++r)
    out[(size_t)(j0+ty+8*r)*H + k0 + tx] = tile[tx][ty+8*r];
}

// enc_proj: 400 blocks x 512 threads; 16 s-rows register-blocked x 512 k.
__global__ __launch_bounds__(512) void k_encproj(const float* __restrict__ enc,
                          const float* __restrict__ Wt,
                          const float* __restrict__ b_energy,
                          float* __restrict__ enc_proj){
  __shared__ float ldsE[16][H];
  const int r0 = blockIdx.x * 16;
  const int tid = threadIdx.x;
  for (int i = tid; i < 16*(H/4); i += 512){
    const int r = i >> 7, cc = i & 127;
    *reinterpret_cast<float4*>(&ldsE[r][cc*4]) =
        *reinterpret_cast<const float4*>(&enc[(size_t)(r0+r)*H + cc*4]);
  }
  __syncthreads();
  const int k = tid;
  float acc[16];
  #pragma unroll
  for (int r=0;r<16;++r) acc[r]=0.0f;
  #pragma unroll 2
  for (int j=0;j<H;j+=4){
    const float w0 = Wt[(size_t) j   *H + k];
    const float w1 = Wt[(size_t)(j+1)*H + k];
    const float w2 = Wt[(size_t)(j+2)*H + k];
    const float w3 = Wt[(size_t)(j+3)*H + k];
    #pragma unroll
    for (int r=0;r<16;++r){
      const float4 e = *reinterpret_cast<const float4*>(&ldsE[r][j]);
      acc[r] += e.x*w0 + e.y*w1 + e.z*w2 + e.w*w3;
    }
  }
  const float be = b_energy[k];
  #pragma unroll
  for (int r=0;r<16;++r) enc_proj[(size_t)(r0+r)*H + k] = acc[r] + be;
}

// grid 64 x 256: gates GEMM multi-b (16 j x 4 gates x 8 b) + fused LSTM.
// Blocks 0..15 also zero xnext for this step's ctxpost atomics.
__global__ __launch_bounds__(256) void k_gates(
    const float* __restrict__ x, const float* __restrict__ hold,
    const float* __restrict__ cold,
    const float* __restrict__ W_ih, const float* __restrict__ W_hh,
    const float* __restrict__ b_ih, const float* __restrict__ b_hh,
    float* __restrict__ hnew, float* __restrict__ cnew,
    float* __restrict__ xnext){
  const int blk = blockIdx.x, tid = threadIdx.x;
  if (blk < 16 && tid < E) xnext[blk*E + tid] = 0.0f;
  const int gb = blk >> 1, bh = blk & 1, b0 = bh*8;
  __shared__ float xh[8][640];
  __shared__ float sg[4][64][9];
  for (int b=0;b<8;++b)
    for (int k=tid;k<640;k+=256)
      xh[b][k] = (k<E) ? x[(b0+b)*E + k] : hold[(b0+b)*H + (k-E)];
  __syncthreads();
  const int w = tid >> 6, l = tid & 63, g = l >> 4, jj = l & 15;
  const int row = g*H + gb*16 + jj;
  float acc[8];
  #pragma unroll
  for (int b=0;b<8;++b) acc[b]=0.0f;
  const int ks = w*160, ke = ks + 160;
  if (ks < 128){
    const float* wr = W_ih + (size_t)row*E;
    for (int k=0;k<128;k+=4){
      const float4 wv = *reinterpret_cast<const float4*>(wr + k);
      #pragma unroll
      for (int b=0;b<8;++b){
        const float4 xv = *reinterpret_cast<const float4*>(&xh[b][k]);
        acc[b] += xv.x*wv.x + xv.y*wv.y + xv.z*wv.z + xv.w*wv.w;
      }
    }
  }
  {
    const int hs = (ks < 128) ? 128 : ks;
    const float* wr = W_hh + (size_t)row*H - 128;
    for (int k=hs;k<ke;k+=4){
      const float4 wv = *reinterpret_cast<const float4*>(wr + k);
      #pragma unroll
      for (int b=0;b<8;++b){
        const float4 xv = *reinterpret_cast<const float4*>(&xh[b][k]);
        acc[b] += xv.x*wv.x + xv.y*wv.y + xv.z*wv.z + xv.w*wv.w;
      }
    }
  }
  #pragma unroll
  for (int b=0;b<8;++b) sg[w][l][b] = acc[b];
  __syncthreads();
  if (tid < 128){
    const int b = tid >> 4, j2 = tid & 15;
    float gs[4];
    #pragma unroll
    for (int g2=0;g2<4;++g2){
      const int ll = g2*16 + j2;
      const int rw = g2*H + gb*16 + j2;
      gs[g2] = sg[0][ll][b]+sg[1][ll][b]+sg[2][ll][b]+sg[3][ll][b] + b_ih[rw] + b_hh[rw];
    }
    const float ig = fsig(gs[0]);
    const float fg = fsig(gs[1]);
    const float gg = ftanh(gs[2]);
    const float og = fsig(gs[3]);
    const int idx = (b0+b)*H + gb*16 + j2;
    const float cn = fg*cold[idx] + ig*gg;
    cnew[idx] = cn;
    hnew[idx] = og*ftanh(cn);
  }
}

// dec = h @ W_d^T via coalesced WdT. grid 64 x 256: blk = jc*8 + bp (2 b each).
__global__ __launch_bounds__(256) void k_dec(const float* __restrict__ h,
    const float* __restrict__ WdT, float* __restrict__ dec){
  const int blk = blockIdx.x, tid = threadIdx.x;
  const int jc = blk >> 3, bp = blk & 7, b0 = bp*2;
  __shared__ float sh[2][H];
  __shared__ float r[4][64][2];
  for (int i=tid;i<2*H;i+=256) sh[i>>9][i&511] = h[b0*H + i];
  __syncthreads();
  const int w = tid >> 6, lane = tid & 63;
  const int j = jc*64 + lane;
  float a0=0.0f, a1=0.0f;
  for (int k=w*128;k<w*128+128;++k){
    const float wv = WdT[(size_t)k*H + j];
    a0 += sh[0][k]*wv;
    a1 += sh[1][k]*wv;
  }
  r[w][lane][0]=a0; r[w][lane][1]=a1;
  __syncthreads();
  if (tid < 128){
    const int jl = tid & 63, bb = tid >> 6;
    dec[(b0+bb)*H + jc*64 + jl] = r[0][jl][bb]+r[1][jl][bb]+r[2][jl][bb]+r[3][jl][bb];
  }
}

// grid (100, B), block 256 = 4 waves, one (b,s) per wave.
__global__ __launch_bounds__(256) void k_score(const float* __restrict__ dec_proj,
    const float* __restrict__ enc_proj, const float* __restrict__ W_cov,
    const float* __restrict__ v_attn, const float* __restrict__ cov,
    float* __restrict__ score){
  const int b = blockIdx.y;
  const int wave = threadIdx.x >> 6, lane = threadIdx.x & 63;
  const int s = blockIdx.x*4 + wave;
  const float cv = cov[b*S + s];
  const float* ep = enc_proj + (size_t)(b*S + s)*H;
  const float* dp = dec_proj + b*H;
  float acc = 0.0f;
  const int k0 = lane*8;
  #pragma unroll
  for (int u=0;u<8;++u){
    const int k = k0+u;
    acc += ftanh(dp[k] + ep[k] + cv*W_cov[k]) * v_attn[k];
  }
  #pragma unroll
  for (int off=32; off>0; off>>=1) acc += __shfl_down(acc, off);
  if (lane==0) score[b*S + s] = acc;
}

// grid (16 b, 8 hc) x 256: redundant softmax; ctx slice; split-K atomic
// assembly of hh(t), xnext(t+1), pgen_raw(t). hc0 adds h/emb/bias parts,
// writes probs_all[t], updates cov.
__global__ __launch_bounds__(256) void k_ctxpost(const float* __restrict__ score,
    const float* __restrict__ masks, const float* __restrict__ enc,
    const float* __restrict__ h, const float* __restrict__ xcur,
    const float* __restrict__ emb, int tnext,
    const float* __restrict__ W_ad, const float* __restrict__ b_ad,
    const float* __restrict__ W_pgen, const float* __restrict__ b_pgen,
    const float* __restrict__ W_xctx, const float* __restrict__ b_xctx,
    float* __restrict__ cov, float* __restrict__ probs_t,
    float* __restrict__ hh_t, float* __restrict__ praw_t,
    float* __restrict__ xnext){
  const int b = blockIdx.x, hc = blockIdx.y, tid = threadIdx.x;
  __shared__ float red[256], sp[512], sctx[64], shh[H], se[E];
  if (hc==0){
    for (int i=tid;i<H;i+=256) shh[i] = h[b*H + i];
    if (tid < E) se[tid] = emb[(size_t)(b*T + tnext)*E + tid];
  }
  const float sc0 = (tid < S)      ? score[b*S + tid]       : -1e30f;
  const float sc1 = (tid+256 < S)  ? score[b*S + tid + 256] : -1e30f;
  red[tid] = fmaxf(sc0, sc1);
  __syncthreads();
  for (int off=128; off>0; off>>=1){ if (tid<off) red[tid]=fmaxf(red[tid],red[tid+off]); __syncthreads(); }
  const float mx = red[0];
  __syncthreads();
  const float e0 = (tid < S)     ? __expf(sc0 - mx) : 0.0f;
  const float e1 = (tid+256 < S) ? __expf(sc1 - mx) : 0.0f;
  red[tid] = e0 + e1;
  __syncthreads();
  for (int off=128; off>0; off>>=1){ if (tid<off) red[tid]+=red[tid+off]; __syncthreads(); }
  const float den = red[0];
  __syncthreads();
  const float p0 = (tid < S)     ? (e0/den)*masks[b*S+tid]     : 0.0f;
  const float p1 = (tid+256 < S) ? (e1/den)*masks[b*S+tid+256] : 0.0f;
  red[tid] = p0 + p1;
  __syncthreads();
  for (int off=128; off>0; off>>=1){ if (tid<off) red[tid]+=red[tid+off]; __syncthreads(); }
  const float inv = 1.0f/(red[0] + 1e-12f);
  __syncthreads();
  const float pr0 = p0*inv, pr1 = p1*inv;
  sp[tid] = pr0; sp[tid+256] = pr1;
  if (hc==0){
    if (tid < S){ probs_t[b*S+tid] = pr0; cov[b*S+tid] += pr0; }
    if (tid+256 < S){ probs_t[b*S+tid+256] = pr1; cov[b*S+tid+256] += pr1; }
  }
  __syncthreads();
  // ctx slice: cols [hc*64, hc*64+64)
  {
    const int c = tid & 63, sg_ = tid >> 6;
    const float* eb = enc + (size_t)b*S*H + hc*64 + c;
    float a = 0.0f;
    for (int s=sg_; s<S; s+=4) a += sp[s]*eb[(size_t)s*H];
    red[tid] = a;
    __syncthreads();
    if (tid < 64) sctx[tid] = red[tid]+red[tid+64]+red[tid+128]+red[tid+192];
  }
  __syncthreads();
  // hh: ctx-part (all hc) + h-part & bias (hc0)
  for (int j=tid; j<H; j+=256){
    const float* wa = W_ad + (size_t)j*(2*H) + H + hc*64;
    float acc = 0.0f;
    #pragma unroll
    for (int k=0;k<64;k+=4){
      const float4 w = *reinterpret_cast<const float4*>(wa+k);
      acc += sctx[k]*w.x + sctx[k+1]*w.y + sctx[k+2]*w.z + sctx[k+3]*w.w;
    }
    if (hc==0){
      const float* wh = W_ad + (size_t)j*(2*H);
      #pragma unroll 8
      for (int k=0;k<H;k+=4){
        const float4 w = *reinterpret_cast<const float4*>(wh+k);
        acc += shh[k]*w.x + shh[k+1]*w.y + shh[k+2]*w.z + shh[k+3]*w.w;
      }
      acc += b_ad[j];
    }
    atomicAdd(&hh_t[b*H + j], acc);
  }
  // xnext: ctx-part (all hc) + emb-part & bias (hc0)
  if (tid < E){
    const float* wx = W_xctx + (size_t)tid*(E+H) + E + hc*64;
    float acc = 0.0f;
    #pragma unroll
    for (int k=0;k<64;k+=4){
      const float4 w = *reinterpret_cast<const float4*>(wx+k);
      acc += sctx[k]*w.x + sctx[k+1]*w.y + sctx[k+2]*w.z + sctx[k+3]*w.w;
    }
    if (hc==0){
      const float* we = W_xctx + (size_t)tid*(E+H);
      #pragma unroll 8
      for (int k=0;k<E;k+=4){
        const float4 w = *reinterpret_cast<const float4*>(we+k);
        acc += se[k]*w.x + se[k+1]*w.y + se[k+2]*w.z + se[k+3]*w.w;
      }
      acc += b_xctx[tid];
    }
    atomicAdd(&xnext[b*E + tid], acc);
  }
  // pgen: ctx-part (all hc) + h/x parts & bias (hc0)
  {
    float part = (tid < 64) ? sctx[tid]*W_pgen[hc*64 + tid] : 0.0f;
    if (hc==0){
      for (int k=tid;k<H;k+=256) part += shh[k]*W_pgen[H + k];
      for (int k=tid;k<E;k+=256) part += xcur[b*E + k]*W_pgen[2*H + k];
    }
    __syncthreads();
    red[tid] = part;
    __syncthreads();
    for (int off=128; off>0; off>>=1){ if (tid<off) red[tid]+=red[tid+off]; __syncthreads(); }
    if (tid==0) atomicAdd(&praw_t[b], red[0] + (hc==0 ? b_pgen[0] : 0.0f));
  }
}

// hh_all (fp32) -> bf16
__global__ __launch_bounds__(256) void k_cvt(const float* __restrict__ hh_all,
    unsigned short* __restrict__ hh_bf){
  const int stride = gridDim.x*256;
  for (int i = blockIdx.x*256 + threadIdx.x; i < T*B*H; i += stride)
    hh_bf[i] = f2bf(hh_all[i]);
}

// MFMA vocab GEMM: out = exp(hh_bf . W_vocab^T + b_vocab) (unscaled), rowsums -> vsum.
// Grid 250 x 256 (4 waves, 32 n per wave, all M=512).
__global__ __launch_bounds__(256) void k_vocab_mfma(
    const unsigned short* __restrict__ hh_bf,
    const float* __restrict__ W_vocab, const float* __restrict__ b_vocab,
    float* __restrict__ out, float* __restrict__ vsum){
  const int tid = threadIdx.x, lane = tid & 63, w = tid >> 6;
  const int nl = lane & 15, kg = lane >> 4;
  const int nbase = blockIdx.x*128 + w*32;
  const int n0 = nbase + nl, n1 = nbase + 16 + nl;
  __shared__ float svs[512];
  for (int i=tid;i<512;i+=256) svs[i]=0.0f;
  __syncthreads();
  const float bv0 = b_vocab[n0], bv1 = b_vocab[n1];
  const float* wr0 = W_vocab + (size_t)n0*H;
  const float* wr1 = W_vocab + (size_t)n1*H;
  for (int mc=0; mc<4; ++mc){
    f32x4 acc0[8], acc1[8];
    #pragma unroll
    for (int mf=0;mf<8;++mf){
      acc0[mf] = (f32x4){0.f,0.f,0.f,0.f};
      acc1[mf] = (f32x4){0.f,0.f,0.f,0.f};
    }
    for (int kk=0; kk<16; ++kk){
      const int ko = kk*32 + kg*8;
      short8v bf0, bf1;
      const float4 wa0 = *reinterpret_cast<const float4*>(wr0 + ko);
      const float4 wb0 = *reinterpret_cast<const float4*>(wr0 + ko + 4);
      const float4 wa1 = *reinterpret_cast<const float4*>(wr1 + ko);
      const float4 wb1 = *reinterpret_cast<const float4*>(wr1 + ko + 4);
      bf0[0]=(short)f2bf(wa0.x); bf0[1]=(short)f2bf(wa0.y); bf0[2]=(short)f2bf(wa0.z); bf0[3]=(short)f2bf(wa0.w);
      bf0[4]=(short)f2bf(wb0.x); bf0[5]=(short)f2bf(wb0.y); bf0[6]=(short)f2bf(wb0.z); bf0[7]=(short)f2bf(wb0.w);
      bf1[0]=(short)f2bf(wa1.x); bf1[1]=(short)f2bf(wa1.y); bf1[2]=(short)f2bf(wa1.z); bf1[3]=(short)f2bf(wa1.w);
      bf1[4]=(short)f2bf(wb1.x); bf1[5]=(short)f2bf(wb1.y); bf1[6]=(short)f2bf(wb1.z); bf1[7]=(short)f2bf(wb1.w);
      #pragma unroll
      for (int mf=0;mf<8;++mf){
        const int m = mc*128 + mf*16 + nl;
        const short8v af = *reinterpret_cast<const short8v*>(hh_bf + (size_t)m*H + ko);
        acc0[mf] = __builtin_amdgcn_mfma_f32_16x16x32_bf16(af, bf0, acc0[mf], 0, 0, 0);
        acc1[mf] = __builtin_amdgcn_mfma_f32_16x16x32_bf16(af, bf1, acc1[mf], 0, 0, 0);
      }
    }
    #pragma unroll
    for (int mf=0;mf<8;++mf){
      #pragma unroll
      for (int r=0;r<4;++r){
        const int m = mc*128 + mf*16 + kg*4 + r;   // m = t*16 + b
        const int tq = m >> 4, bq = m & 15;
        const float e0 = __expf(acc0[mf][r] + bv0);
        const float e1 = __expf(acc1[mf][r] + bv1);
        float* orow = out + ((size_t)bq*T + tq)*VEXT;
        orow[n0] = e0;
        orow[n1] = e1;
        float s = e0 + e1;
        #pragma unroll
        for (int off=1; off<16; off<<=1) s += __shfl_xor(s, off);
        if (nl==0) atomicAdd(&svs[m], s);
      }
    }
  }
  __syncthreads();
  for (int i=tid;i<512;i+=256) atomicAdd(&vsum[i], svs[i]);
}

// scale out rows in place + OOV tail. grid (512 rows, 9) x 256.
__global__ __launch_bounds__(256) void k_finalize(const float* __restrict__ praw,
    const float* __restrict__ vsum, const float* __restrict__ exz,
    float* __restrict__ out){
  const int rm = blockIdx.x, vc = blockIdx.y, tid = threadIdx.x;
  const int t = rm >> 4, b = rm & 15;
  float* orow = out + ((size_t)b*T + t)*VEXT;
  if (vc < 8){
    const float scl = fsig(praw[rm]) / vsum[rm];
    const int base = vc*4000;
    for (int i = tid; i < 4000; i += 256) orow[base + i] *= scl;
  } else if (tid < OOV){
    orow[V + tid] = exz[b*OOV + tid];
  }
}

// grid-stride scatter of copy-dist for all steps.
__global__ __launch_bounds__(256) void k_scatter_all(const float* __restrict__ probs_all,
    const float* __restrict__ praw, const int* __restrict__ eidx,
    float* __restrict__ out){
  const int stride = gridDim.x*256;
  for (int i = blockIdx.x*256 + threadIdx.x; i < T*B*S; i += stride){
    const int t = i / (B*S);
    const int rem = i - t*B*S;
    const int b = rem / S, s = rem - b*S;
    const float fac = 1.0f - fsig(praw[t*B + b]);
    float* orow = out + ((size_t)b*T + t)*VEXT;
    atomicAdd(&orow[eidx[b*S + s]], fac*probs_all[(size_t)(t*B + b)*S + s]);
  }
}

} // namespace

extern "C" void kernel_launch(void* const* d_in, const int* in_sizes, int n_in,
                              void* d_out, int out_size, void* d_ws, size_t ws_size,
                              hipStream_t stream){
  const float* emb    = (const float*)d_in[0];
  const float* h0     = (const float*)d_in[1];
  const float* c0     = (const float*)d_in[2];
  const float* enc    = (const float*)d_in[3];
  const float* masks  = (const float*)d_in[4];
  const float* exz    = (const float*)d_in[5];
  const int*   eidx   = (const int*)d_in[6];
  const float* W_ih   = (const float*)d_in[7];
  const float* W_hh   = (const float*)d_in[8];
  const float* b_ih   = (const float*)d_in[9];
  const float* b_hh   = (const float*)d_in[10];
  const float* W_vocab= (const float*)d_in[11];
  const float* b_vocab= (const float*)d_in[12];
  const float* W_cov  = (const float*)d_in[13];
  const float* W_energy=(const float*)d_in[14];
  const float* b_energy=(const float*)d_in[15];
  const float* v_attn = (const float*)d_in[16];
  const float* W_xctx = (const float*)d_in[17];
  const float* b_xctx = (const float*)d_in[18];
  const float* W_ad   = (const float*)d_in[19];
  const float* b_ad   = (const float*)d_in[20];
  const float* W_pgen = (const float*)d_in[21];
  const float* b_pgen = (const float*)d_in[22];

  float* ws = (float*)d_ws;
  float* hbuf     = ws;                 // 2 x 8192
  float* cbuf     = ws + 16384;         // 2 x 8192
  float* xbuf     = ws + 32768;         // 2 x 2048
  float* dec      = ws + 36864;         // 8192
  float* score    = ws + 45056;         // 6400
  float* cov      = ws + 51456;         // 6400
  float* praw     = ws + 57856;         // 512
  float* vsum     = ws + 58368;         // 512
  float* probs_all= ws + 58880;         // 204800
  float* hh_all   = ws + 263680;        // 262144
  float* WdT      = ws + 525824;        // 262144
  float* Wt       = ws + 787968;        // 262144
  float* hh_bf_f  = ws + 1050112;       // 131072 floats = 262144 ushort
  float* encp     = ws + 1181184;       // 3276800
  unsigned short* hh_bf = (unsigned short*)hh_bf_f;
  float* outp     = (float*)d_out;

  k_init<<<300,256,0,stream>>>(h0,c0,hbuf,cbuf,cov,praw,vsum,hh_all);
  k_x0<<<16,128,0,stream>>>(emb,W_xctx,b_xctx,xbuf);
  k_trw<<<dim3(16,16),256,0,stream>>>(W_energy,Wt,H);    // W_e^T for encproj
  k_trw<<<dim3(16,16),256,0,stream>>>(W_energy,WdT,0);   // W_d^T for dec GEMV
  k_encproj<<<400,512,0,stream>>>(enc,Wt,b_energy,encp);

  for (int t=0;t<T;++t){
    const int p = t&1;
    const float* hold = hbuf + p*8192;
    const float* cold = cbuf + p*8192;
    float* hnew = hbuf + (p^1)*8192;
    float* cnew = cbuf + (p^1)*8192;
    const float* xcur = xbuf + p*2048;
    float* xnext = xbuf + (p^1)*2048;
    const int tnext = (t+1 < T) ? (t+1) : (T-1);
    k_gates<<<64,256,0,stream>>>(xcur,hold,cold,W_ih,W_hh,b_ih,b_hh,hnew,cnew,xnext);
    k_dec<<<64,256,0,stream>>>(hnew,WdT,dec);
    k_score<<<dim3(100,16),256,0,stream>>>(dec,encp,W_cov,v_attn,cov,score);
    k_ctxpost<<<dim3(16,8),256,0,stream>>>(score,masks,enc,hnew,xcur,emb,tnext,
        W_ad,b_ad,W_pgen,b_pgen,W_xctx,b_xctx,
        cov,probs_all + (size_t)t*B*S, hh_all + (size_t)t*B*H, praw + t*B, xnext);
  }

  k_cvt<<<256,256,0,stream>>>(hh_all,hh_bf);
  k_vocab_mfma<<<250,256,0,stream>>>(hh_bf,W_vocab,b_vocab,outp,vsum);
  k_finalize<<<dim3(512,9),256,0,stream>>>(praw,vsum,exz,outp);
  k_scatter_all<<<200,256,0,stream>>>(probs_all,praw,eidx,outp);
}

// Round 7
// 2588.244 us; speedup vs baseline: 2.7865x; 1.3814x over previous
//
#include <hip/hip_runtime.h>
#include <hip/hip_bf16.h>
#include <cstddef>

namespace {

constexpr int B = 16, T = 32, S = 400, E = 128, H = 512, V = 32000, OOV = 50, VEXT = V + OOV;

typedef __attribute__((ext_vector_type(8))) short short8v;
typedef __attribute__((ext_vector_type(4))) float f32x4;

__device__ __forceinline__ float fsig(float x){ return 1.0f/(1.0f+__expf(-x)); }
__device__ __forceinline__ float ftanh(float x){
  float ax = fabsf(x);
  float t = __expf(-2.0f*ax);
  float r = (1.0f - t)/(1.0f + t);
  return copysignf(r, x);
}
__device__ __forceinline__ unsigned short f2bf(float f){   // round-to-nearest-even
  unsigned int u = __float_as_uint(f);
  unsigned int r = (u + 0x7FFFu + ((u >> 16) & 1u)) >> 16;
  return (unsigned short)r;
}

// grid-stride init: copy h0/c0, zero cov, praw, vsum, hh_all.
__global__ __launch_bounds__(256) void k_init(const float* __restrict__ h0, const float* __restrict__ c0,
    float* __restrict__ h, float* __restrict__ c, float* __restrict__ cov,
    float* __restrict__ praw, float* __restrict__ vsum, float* __restrict__ hh_all){
  const int stride = gridDim.x*256;
  for (int i = blockIdx.x*256 + threadIdx.x; i < T*B*H; i += stride){
    hh_all[i] = 0.0f;
    if (i < B*H){ h[i]=h0[i]; c[i]=c0[i]; }
    if (i < B*S) cov[i]=0.0f;
    if (i < T*B){ praw[i]=0.0f; vsum[i]=0.0f; }
  }
}

// x0[b][j] = emb[b][0][:] . W_xctx[j][:E] + b_xctx[j]   (ctx_0 = 0)
__global__ __launch_bounds__(128) void k_x0(const float* __restrict__ emb,
    const float* __restrict__ W_xctx, const float* __restrict__ b_xctx,
    float* __restrict__ x0){
  const int b = blockIdx.x, tid = threadIdx.x;
  __shared__ float se[E];
  se[tid] = emb[(size_t)(b*T)*E + tid];
  __syncthreads();
  const float* w = W_xctx + (size_t)tid*(E+H);
  float acc = b_xctx[tid];
  #pragma unroll 8
  for (int k=0;k<E;k+=4){
    float4 wv = *reinterpret_cast<const float4*>(w+k);
    acc += se[k]*wv.x + se[k+1]*wv.y + se[k+2]*wv.z + se[k+3]*wv.w;
  }
  x0[b*E + tid] = acc;
}

// OUT[a][b] = W_energy[b][off+a], a,b in [0,512). grid (16,16) x 256.
__global__ __launch_bounds__(256) void k_trw(const float* __restrict__ W_energy,
                                             float* __restrict__ out, int off){
  __shared__ float tile[32][33];
  const int j0 = blockIdx.x*32, k0 = blockIdx.y*32;
  const int tx = threadIdx.x & 31, ty = threadIdx.x >> 5;
  #pragma unroll
  for (int r=0;r<4;++r)
    tile[ty+8*r][tx] = W_energy[(size_t)(k0+ty+8*r)*(2*H) + off + j0 + tx];
  __syncthreads();
  #pragma unroll
  for (int r=0;r<4;++r)
    out[(size_t)(j0+ty+8*r)*H + k0 + tx] = tile[tx][ty+8*r];
}

// enc_proj v2: 400 blocks x 512 threads (k=tid); enc values via wave-uniform
// scalar loads (no LDS), Wt loads coalesced across k.
__global__ __launch_bounds__(512) void k_encproj(const float* __restrict__ enc,
                          const float* __restrict__ Wt,
                          const float* __restrict__ b_energy,
                          float* __restrict__ enc_proj){
  const int r0 = blockIdx.x*16, k = threadIdx.x;
  const float* eb = enc + (size_t)r0*H;
  float acc[16];
  #pragma unroll
  for (int r=0;r<16;++r) acc[r]=0.0f;
  for (int j=0;j<H;j+=4){
    const float w0 = Wt[(size_t) j   *H + k];
    const float w1 = Wt[(size_t)(j+1)*H + k];
    const float w2 = Wt[(size_t)(j+2)*H + k];
    const float w3 = Wt[(size_t)(j+3)*H + k];
    #pragma unroll
    for (int r=0;r<16;++r){
      acc[r] += eb[(size_t)r*H + j]*w0 + eb[(size_t)r*H + j+1]*w1
              + eb[(size_t)r*H + j+2]*w2 + eb[(size_t)r*H + j+3]*w3;
    }
  }
  const float be = b_energy[k];
  #pragma unroll
  for (int r=0;r<16;++r) enc_proj[(size_t)(r0+r)*H + k] = acc[r] + be;
}

// grid 256 x 256: gates partial GEMM. blk -> (gbh = blk>>2: 64 row/b groups, kh = blk&3).
// Writes partial sums (no atomics) to gpart[kh][b][row].
__global__ __launch_bounds__(256) void k_gates2(
    const float* __restrict__ x, const float* __restrict__ hold,
    const float* __restrict__ W_ih, const float* __restrict__ W_hh,
    float* __restrict__ gpart){
  const int blk = blockIdx.x, tid = threadIdx.x;
  const int gbh = blk >> 2, kh = blk & 3;
  const int gb = gbh >> 1, bh = gbh & 1, b0 = bh*8;
  __shared__ float xh[8][640];
  __shared__ float sg[4][64][9];
  for (int b=0;b<8;++b)
    for (int k=tid;k<640;k+=256)
      xh[b][k] = (k<E) ? x[(b0+b)*E + k] : hold[(b0+b)*H + (k-E)];
  __syncthreads();
  const int w = tid >> 6, l = tid & 63, g = l >> 4, jj = l & 15;
  const int row = g*H + gb*16 + jj;
  float acc[8];
  #pragma unroll
  for (int b=0;b<8;++b) acc[b]=0.0f;
  const int ks = kh*160 + w*40, ke = ks + 40;
  const int k1 = (ke < 128) ? ke : 128;
  if (ks < 128){
    const float* wr = W_ih + (size_t)row*E;
    for (int k=ks; k<k1; k+=4){
      const float4 wv = *reinterpret_cast<const float4*>(wr + k);
      #pragma unroll
      for (int b=0;b<8;++b){
        const float4 xv = *reinterpret_cast<const float4*>(&xh[b][k]);
        acc[b] += xv.x*wv.x + xv.y*wv.y + xv.z*wv.z + xv.w*wv.w;
      }
    }
  }
  const int k2 = (ks > 128) ? ks : 128;
  if (k2 < ke){
    const float* wr = W_hh + (size_t)row*H - 128;   // wr[k] == W_hh[row][k-128]
    for (int k=k2; k<ke; k+=4){
      const float4 wv = *reinterpret_cast<const float4*>(wr + k);
      #pragma unroll
      for (int b=0;b<8;++b){
        const float4 xv = *reinterpret_cast<const float4*>(&xh[b][k]);
        acc[b] += xv.x*wv.x + xv.y*wv.y + xv.z*wv.z + xv.w*wv.w;
      }
    }
  }
  #pragma unroll
  for (int b=0;b<8;++b) sg[w][l][b] = acc[b];
  __syncthreads();
  for (int i=tid; i<512; i+=256){
    const int l2 = i & 63, b = i >> 6;
    const int g2 = l2 >> 4, j2 = l2 & 15;
    const int row2 = g2*H + gb*16 + j2;
    gpart[((size_t)kh*B + (b0+b))*(4*H) + row2] =
        sg[0][l2][b]+sg[1][l2][b]+sg[2][l2][b]+sg[3][l2][b];
  }
}

// grid 64 x 256 (jc=blk>>3, bp=blk&7): LSTM from gpart (redundant x8, benign
// duplicate hnew/cnew writes) then dec GEMV slice via coalesced WdT.
__global__ __launch_bounds__(256) void k_dec2(const float* __restrict__ gpart,
    const float* __restrict__ cold, const float* __restrict__ b_ih,
    const float* __restrict__ b_hh, const float* __restrict__ WdT,
    float* __restrict__ cnew, float* __restrict__ hnew, float* __restrict__ dec){
  const int blk = blockIdx.x, tid = threadIdx.x;
  const int jc = blk >> 3, bp = blk & 7, b0 = bp*2;
  __shared__ float sh[2][H];
  __shared__ float r[4][64][2];
  for (int i=tid; i<2*H; i+=256){
    const int bl = i >> 9, j = i & 511;
    const int b = b0 + bl;
    float gs[4];
    #pragma unroll
    for (int g=0; g<4; ++g){
      const int row = g*H + j;
      float v = b_ih[row] + b_hh[row];
      #pragma unroll
      for (int kh=0; kh<4; ++kh) v += gpart[((size_t)kh*B + b)*(4*H) + row];
      gs[g] = v;
    }
    const float ig = fsig(gs[0]);
    const float fg = fsig(gs[1]);
    const float gg = ftanh(gs[2]);
    const float og = fsig(gs[3]);
    const float cn = fg*cold[b*H + j] + ig*gg;
    const float hn = og*ftanh(cn);
    cnew[b*H + j] = cn;
    hnew[b*H + j] = hn;
    sh[bl][j] = hn;
  }
  __syncthreads();
  const int w = tid >> 6, lane = tid & 63;
  const int j = jc*64 + lane;
  float a0=0.0f, a1=0.0f;
  for (int k=w*128; k<w*128+128; ++k){
    const float wv = WdT[(size_t)k*H + j];
    a0 += sh[0][k]*wv;
    a1 += sh[1][k]*wv;
  }
  r[w][lane][0]=a0; r[w][lane][1]=a1;
  __syncthreads();
  if (tid < 128){
    const int jl = tid & 63, bb = tid >> 6;
    dec[(b0+bb)*H + jc*64 + jl] = r[0][jl][bb]+r[1][jl][bb]+r[2][jl][bb]+r[3][jl][bb];
  }
}

// grid (100, B), block 256 = 4 waves, one (b,s) per wave. blockIdx.x==0 zeroes xnext.
__global__ __launch_bounds__(256) void k_score(const float* __restrict__ dec_proj,
    const float* __restrict__ enc_proj, const float* __restrict__ W_cov,
    const float* __restrict__ v_attn, const float* __restrict__ cov,
    float* __restrict__ score, float* __restrict__ xnext){
  const int b = blockIdx.y;
  if (blockIdx.x==0 && threadIdx.x < E) xnext[b*E + threadIdx.x] = 0.0f;
  const int wave = threadIdx.x >> 6, lane = threadIdx.x & 63;
  const int s = blockIdx.x*4 + wave;
  const float cv = cov[b*S + s];
  const float* ep = enc_proj + (size_t)(b*S + s)*H;
  const float* dp = dec_proj + b*H;
  float acc = 0.0f;
  const int k0 = lane*8;
  #pragma unroll
  for (int u=0;u<8;++u){
    const int k = k0+u;
    acc += ftanh(dp[k] + ep[k] + cv*W_cov[k]) * v_attn[k];
  }
  #pragma unroll
  for (int off=32; off>0; off>>=1) acc += __shfl_down(acc, off);
  if (lane==0) score[b*S + s] = acc;
}

// grid (16 b, 8 hc) x 256: softmax; ctx slice; BALANCED split-K assembly of
// hh(t), xnext(t+1), pgen(t): each hc handles its 64-col slice of both the
// ctx-part AND the h-part (and 16-col slice of emb/x parts).
__global__ __launch_bounds__(256) void k_ctxpost(const float* __restrict__ score,
    const float* __restrict__ masks, const float* __restrict__ enc,
    const float* __restrict__ h, const float* __restrict__ xcur,
    const float* __restrict__ emb, int tnext,
    const float* __restrict__ W_ad, const float* __restrict__ b_ad,
    const float* __restrict__ W_pgen, const float* __restrict__ b_pgen,
    const float* __restrict__ W_xctx, const float* __restrict__ b_xctx,
    float* __restrict__ cov, float* __restrict__ probs_t,
    float* __restrict__ hh_t, float* __restrict__ praw_t,
    float* __restrict__ xnext){
  const int b = blockIdx.x, hc = blockIdx.y, tid = threadIdx.x;
  __shared__ float red[256], sp[512], sctx[64], shh[H], se[E];
  for (int i=tid;i<H;i+=256) shh[i] = h[b*H + i];
  if (tid < E) se[tid] = emb[(size_t)(b*T + tnext)*E + tid];
  const float sc0 = (tid < S)      ? score[b*S + tid]       : -1e30f;
  const float sc1 = (tid+256 < S)  ? score[b*S + tid + 256] : -1e30f;
  red[tid] = fmaxf(sc0, sc1);
  __syncthreads();
  for (int off=128; off>0; off>>=1){ if (tid<off) red[tid]=fmaxf(red[tid],red[tid+off]); __syncthreads(); }
  const float mx = red[0];
  __syncthreads();
  const float e0 = (tid < S)     ? __expf(sc0 - mx) : 0.0f;
  const float e1 = (tid+256 < S) ? __expf(sc1 - mx) : 0.0f;
  red[tid] = e0 + e1;
  __syncthreads();
  for (int off=128; off>0; off>>=1){ if (tid<off) red[tid]+=red[tid+off]; __syncthreads(); }
  const float den = red[0];
  __syncthreads();
  const float p0 = (tid < S)     ? (e0/den)*masks[b*S+tid]     : 0.0f;
  const float p1 = (tid+256 < S) ? (e1/den)*masks[b*S+tid+256] : 0.0f;
  red[tid] = p0 + p1;
  __syncthreads();
  for (int off=128; off>0; off>>=1){ if (tid<off) red[tid]+=red[tid+off]; __syncthreads(); }
  const float inv = 1.0f/(red[0] + 1e-12f);
  __syncthreads();
  const float pr0 = p0*inv, pr1 = p1*inv;
  sp[tid] = pr0; sp[tid+256] = pr1;
  if (hc==0){
    if (tid < S){ probs_t[b*S+tid] = pr0; cov[b*S+tid] += pr0; }
    if (tid+256 < S){ probs_t[b*S+tid+256] = pr1; cov[b*S+tid+256] += pr1; }
  }
  __syncthreads();
  // ctx slice: cols [hc*64, hc*64+64)
  {
    const int c = tid & 63, sg_ = tid >> 6;
    const float* eb = enc + (size_t)b*S*H + hc*64 + c;
    float a = 0.0f;
    for (int s=sg_; s<S; s+=4) a += sp[s]*eb[(size_t)s*H];
    red[tid] = a;
    __syncthreads();
    if (tid < 64) sctx[tid] = red[tid]+red[tid+64]+red[tid+128]+red[tid+192];
  }
  __syncthreads();
  // hh: ctx-slice + h-slice (balanced); bias on hc0
  for (int j=tid; j<H; j+=256){
    const float* wr = W_ad + (size_t)j*(2*H);
    float acc = 0.0f;
    #pragma unroll
    for (int k=0;k<64;k+=4){
      const float4 wc = *reinterpret_cast<const float4*>(wr + H + hc*64 + k);
      acc += sctx[k]*wc.x + sctx[k+1]*wc.y + sctx[k+2]*wc.z + sctx[k+3]*wc.w;
      const float4 wh = *reinterpret_cast<const float4*>(wr + hc*64 + k);
      const float* hb = shh + hc*64 + k;
      acc += hb[0]*wh.x + hb[1]*wh.y + hb[2]*wh.z + hb[3]*wh.w;
    }
    if (hc==0) acc += b_ad[j];
    atomicAdd(&hh_t[b*H + j], acc);
  }
  // xnext: ctx-slice (64) + emb-slice (16); bias on hc0
  if (tid < E){
    const float* wr = W_xctx + (size_t)tid*(E+H);
    float acc = 0.0f;
    #pragma unroll
    for (int k=0;k<64;k+=4){
      const float4 wc = *reinterpret_cast<const float4*>(wr + E + hc*64 + k);
      acc += sctx[k]*wc.x + sctx[k+1]*wc.y + sctx[k+2]*wc.z + sctx[k+3]*wc.w;
    }
    #pragma unroll
    for (int k=0;k<16;k+=4){
      const float4 we = *reinterpret_cast<const float4*>(wr + hc*16 + k);
      const float* eb2 = se + hc*16 + k;
      acc += eb2[0]*we.x + eb2[1]*we.y + eb2[2]*we.z + eb2[3]*we.w;
    }
    if (hc==0) acc += b_xctx[tid];
    atomicAdd(&xnext[b*E + tid], acc);
  }
  // pgen: ctx-slice + h-slice + x-slice
  {
    float part = 0.0f;
    if (tid < 64){
      part = sctx[tid]*W_pgen[hc*64 + tid] + shh[hc*64 + tid]*W_pgen[H + hc*64 + tid];
      if (tid < 16) part += xcur[b*E + hc*16 + tid]*W_pgen[2*H + hc*16 + tid];
    }
    __syncthreads();
    red[tid] = part;
    __syncthreads();
    for (int off=128; off>0; off>>=1){ if (tid<off) red[tid]+=red[tid+off]; __syncthreads(); }
    if (tid==0) atomicAdd(&praw_t[b], red[0] + (hc==0 ? b_pgen[0] : 0.0f));
  }
}

// hh_all (fp32) -> bf16
__global__ __launch_bounds__(256) void k_cvt(const float* __restrict__ hh_all,
    unsigned short* __restrict__ hh_bf){
  const int stride = gridDim.x*256;
  for (int i = blockIdx.x*256 + threadIdx.x; i < T*B*H; i += stride)
    hh_bf[i] = f2bf(hh_all[i]);
}

// MFMA vocab GEMM v2: W tiles staged coalesced into LDS (bf16, fragment layout).
// Grid 500 x 256 (4 waves). Block: 64 n-cols (wave w -> n-tile w), all M=512.
__global__ __launch_bounds__(256) void k_vocab2(
    const unsigned short* __restrict__ hh_bf,
    const float* __restrict__ W_vocab, const float* __restrict__ b_vocab,
    float* __restrict__ out, float* __restrict__ vsum){
  __shared__ unsigned short sw[4][4][512];   // [nt_l][kb_l][(kg*16+nl)*8+e]
  __shared__ float svs[512];
  const int tid = threadIdx.x, lane = tid & 63, w = tid >> 6;
  const int nl = lane & 15, kg = lane >> 4;
  const int n0 = blockIdx.x*64;
  for (int i=tid;i<512;i+=256) svs[i]=0.0f;
  f32x4 acc[32];
  #pragma unroll
  for (int mt=0;mt<32;++mt) acc[mt] = (f32x4){0.f,0.f,0.f,0.f};
  for (int kc=0; kc<4; ++kc){
    __syncthreads();
    // stage 64 rows x 128 k (coalesced float4), convert to bf16 fragment layout
    for (int i=tid; i<2048; i+=256){
      const int row = i >> 5, c4 = i & 31;
      const float4 v = *reinterpret_cast<const float4*>(
          W_vocab + (size_t)(n0+row)*H + kc*128 + c4*4);
      const int nt_l = row >> 4, nl_r = row & 15;
      const int kb_l = c4 >> 3, kgl = (c4 >> 1) & 3, e0 = (c4 & 1)*4;
      ushort4 u;
      u.x = f2bf(v.x); u.y = f2bf(v.y); u.z = f2bf(v.z); u.w = f2bf(v.w);
      *reinterpret_cast<ushort4*>(&sw[nt_l][kb_l][(kgl*16 + nl_r)*8 + e0]) = u;
    }
    __syncthreads();
    #pragma unroll
    for (int kb_l=0; kb_l<4; ++kb_l){
      const short8v bf = *reinterpret_cast<const short8v*>(&sw[w][kb_l][lane*8]);
      const unsigned short* abase = hh_bf + (kc*4 + kb_l)*32 + kg*8 + (size_t)nl*H;
      #pragma unroll
      for (int mt=0; mt<32; ++mt){
        const short8v af = *reinterpret_cast<const short8v*>(abase + (size_t)mt*16*H);
        acc[mt] = __builtin_amdgcn_mfma_f32_16x16x32_bf16(af, bf, acc[mt], 0, 0, 0);
      }
    }
  }
  // epilogue: exp, write out (unscaled), row-sum partials
  const int n = n0 + w*16 + nl;
  const float bv = b_vocab[n];
  #pragma unroll
  for (int mt=0; mt<32; ++mt){
    #pragma unroll
    for (int r=0;r<4;++r){
      const int m = mt*16 + kg*4 + r;     // m = t*16 + b
      const int tq = m >> 4, bq = m & 15;
      const float e = __expf(acc[mt][r] + bv);
      out[((size_t)bq*T + tq)*VEXT + n] = e;
      float s = e;
      s += __shfl_xor(s, 1);
      s += __shfl_xor(s, 2);
      s += __shfl_xor(s, 4);
      s += __shfl_xor(s, 8);
      if (nl==0) atomicAdd(&svs[m], s);
    }
  }
  __syncthreads();
  for (int i=tid;i<512;i+=256) atomicAdd(&vsum[i], svs[i]);
}

// scale out rows in place + OOV tail. grid (512 rows, 9) x 256.
__global__ __launch_bounds__(256) void k_finalize(const float* __restrict__ praw,
    const float* __restrict__ vsum, const float* __restrict__ exz,
    float* __restrict__ out){
  const int rm = blockIdx.x, vc = blockIdx.y, tid = threadIdx.x;
  const int t = rm >> 4, b = rm & 15;
  float* orow = out + ((size_t)b*T + t)*VEXT;
  if (vc < 8){
    const float scl = fsig(praw[rm]) / vsum[rm];
    const int base = vc*4000;
    for (int i = tid; i < 4000; i += 256) orow[base + i] *= scl;
  } else if (tid < OOV){
    orow[V + tid] = exz[b*OOV + tid];
  }
}

// grid-stride scatter of copy-dist for all steps.
__global__ __launch_bounds__(256) void k_scatter_all(const float* __restrict__ probs_all,
    const float* __restrict__ praw, const int* __restrict__ eidx,
    float* __restrict__ out){
  const int stride = gridDim.x*256;
  for (int i = blockIdx.x*256 + threadIdx.x; i < T*B*S; i += stride){
    const int t = i / (B*S);
    const int rem = i - t*B*S;
    const int b = rem / S, s = rem - b*S;
    const float fac = 1.0f - fsig(praw[t*B + b]);
    float* orow = out + ((size_t)b*T + t)*VEXT;
    atomicAdd(&orow[eidx[b*S + s]], fac*probs_all[(size_t)(t*B + b)*S + s]);
  }
}

} // namespace

extern "C" void kernel_launch(void* const* d_in, const int* in_sizes, int n_in,
                              void* d_out, int out_size, void* d_ws, size_t ws_size,
                              hipStream_t stream){
  const float* emb    = (const float*)d_in[0];
  const float* h0     = (const float*)d_in[1];
  const float* c0     = (const float*)d_in[2];
  const float* enc    = (const float*)d_in[3];
  const float* masks  = (const float*)d_in[4];
  const float* exz    = (const float*)d_in[5];
  const int*   eidx   = (const int*)d_in[6];
  const float* W_ih   = (const float*)d_in[7];
  const float* W_hh   = (const float*)d_in[8];
  const float* b_ih   = (const float*)d_in[9];
  const float* b_hh   = (const float*)d_in[10];
  const float* W_vocab= (const float*)d_in[11];
  const float* b_vocab= (const float*)d_in[12];
  const float* W_cov  = (const float*)d_in[13];
  const float* W_energy=(const float*)d_in[14];
  const float* b_energy=(const float*)d_in[15];
  const float* v_attn = (const float*)d_in[16];
  const float* W_xctx = (const float*)d_in[17];
  const float* b_xctx = (const float*)d_in[18];
  const float* W_ad   = (const float*)d_in[19];
  const float* b_ad   = (const float*)d_in[20];
  const float* W_pgen = (const float*)d_in[21];
  const float* b_pgen = (const float*)d_in[22];

  float* ws = (float*)d_ws;
  float* hbuf     = ws;                 // 2 x 8192
  float* cbuf     = ws + 16384;         // 2 x 8192
  float* xbuf     = ws + 32768;         // 2 x 2048
  float* dec      = ws + 36864;         // 8192
  float* score    = ws + 45056;         // 6400
  float* cov      = ws + 51456;         // 6400
  float* praw     = ws + 57856;         // 512
  float* vsum     = ws + 58368;         // 512
  float* probs_all= ws + 58880;         // 204800
  float* hh_all   = ws + 263680;        // 262144
  float* WdT      = ws + 525824;        // 262144
  float* Wt       = ws + 787968;        // 262144
  float* hh_bf_f  = ws + 1050112;       // 131072 floats = 262144 ushort
  float* gpart    = ws + 1181184;       // 4*16*2048 = 131072
  float* encp     = ws + 1312256;       // 3276800
  unsigned short* hh_bf = (unsigned short*)hh_bf_f;
  float* outp     = (float*)d_out;

  k_init<<<300,256,0,stream>>>(h0,c0,hbuf,cbuf,cov,praw,vsum,hh_all);
  k_x0<<<16,128,0,stream>>>(emb,W_xctx,b_xctx,xbuf);
  k_trw<<<dim3(16,16),256,0,stream>>>(W_energy,Wt,H);    // W_e^T for encproj
  k_trw<<<dim3(16,16),256,0,stream>>>(W_energy,WdT,0);   // W_d^T for dec GEMV
  k_encproj<<<400,512,0,stream>>>(enc,Wt,b_energy,encp);

  for (int t=0;t<T;++t){
    const int p = t&1;
    const float* hold = hbuf + p*8192;
    const float* cold = cbuf + p*8192;
    float* hnew = hbuf + (p^1)*8192;
    float* cnew = cbuf + (p^1)*8192;
    const float* xcur = xbuf + p*2048;
    float* xnext = xbuf + (p^1)*2048;
    const int tnext = (t+1 < T) ? (t+1) : (T-1);
    k_gates2<<<256,256,0,stream>>>(xcur,hold,W_ih,W_hh,gpart);
    k_dec2<<<64,256,0,stream>>>(gpart,cold,b_ih,b_hh,WdT,cnew,hnew,dec);
    k_score<<<dim3(100,16),256,0,stream>>>(dec,encp,W_cov,v_attn,cov,score,xnext);
    k_ctxpost<<<dim3(16,8),256,0,stream>>>(score,masks,enc,hnew,xcur,emb,tnext,
        W_ad,b_ad,W_pgen,b_pgen,W_xctx,b_xctx,
        cov,probs_all + (size_t)t*B*S, hh_all + (size_t)t*B*H, praw + t*B, xnext);
  }

  k_cvt<<<256,256,0,stream>>>(hh_all,hh_bf);
  k_vocab2<<<500,256,0,stream>>>(hh_bf,W_vocab,b_vocab,outp,vsum);
  k_finalize<<<dim3(512,9),256,0,stream>>>(praw,vsum,exz,outp);
  k_scatter_all<<<200,256,0,stream>>>(probs_all,praw,eidx,outp);
}